// Round 7
// baseline (317.923 us; speedup 1.0000x reference)
//
#include <hip/hip_runtime.h>

#define NN    50000
#define ERAW  800000
#define ETOT  850000
#define NBUCK 782            // ceil(NN/64) buckets of 64 dst nodes
#define EPB_A 8192           // edges per block in bucketing passes
#define NBLK_A ((ETOT + EPB_A - 1) / EPB_A)   // 104
#define NCNT  (NBUCK * 64)   // 50048 (padded per-dst count array)

__device__ __forceinline__ void edge_sd(const int* __restrict__ ei, int e, int& s, int& d) {
    if (e < ERAW) { s = ei[e]; d = ei[ERAW + e]; }
    else { int n = e - ERAW; s = n; d = n; }
}

// bf16 pack/unpack (RNE), 2 elements per uint: low16 = a, high16 = b
__device__ __forceinline__ unsigned pack_bf16x2(float a, float b) {
    unsigned ua = __float_as_uint(a), ub = __float_as_uint(b);
    ua += 0x7fffu + ((ua >> 16) & 1u);
    ub += 0x7fffu + ((ub >> 16) & 1u);
    return (ua >> 16) | (ub & 0xffff0000u);
}
__device__ __forceinline__ float2 unpack_bf16x2(unsigned v) {
    float2 r;
    r.x = __uint_as_float(v << 16);
    r.y = __uint_as_float(v & 0xffff0000u);
    return r;
}

// ---------------- CSR build: two-level bucketed counting sort ----------------
__global__ __launch_bounds__(256) void kA1(const int* __restrict__ ei, int* __restrict__ bucket_cnt) {
    __shared__ int lb[NBUCK];
    int t = threadIdx.x;
    for (int i = t; i < NBUCK; i += 256) lb[i] = 0;
    __syncthreads();
    int base = blockIdx.x * EPB_A;
    #pragma unroll 4
    for (int k = 0; k < EPB_A / 256; ++k) {
        int e = base + k * 256 + t;
        if (e < ETOT) {
            int s, d; edge_sd(ei, e, s, d); (void)s;
            atomicAdd(&lb[d >> 6], 1);
        }
    }
    __syncthreads();
    for (int i = t; i < NBUCK; i += 256) if (lb[i]) atomicAdd(&bucket_cnt[i], lb[i]);
}

__global__ void kA2(const int* __restrict__ bucket_cnt, int* __restrict__ bucket_off,
                    int* __restrict__ bucket_cur) {
    __shared__ int tmp[1024];
    int t = threadIdx.x;
    int v = (t < NBUCK) ? bucket_cnt[t] : 0;
    tmp[t] = v;
    __syncthreads();
    for (int off = 1; off < 1024; off <<= 1) {
        int u = (t >= off) ? tmp[t - off] : 0;
        __syncthreads();
        tmp[t] += u;
        __syncthreads();
    }
    if (t < NBUCK) { int ex = tmp[t] - v; bucket_off[t] = ex; bucket_cur[t] = ex; }
    if (t == 0) bucket_off[NBUCK] = ETOT;
}

__global__ __launch_bounds__(256) void kA3(const int* __restrict__ ei, int* __restrict__ bucket_cur,
                                           unsigned* __restrict__ ebkt) {
    __shared__ int lb[NBUCK];
    int t = threadIdx.x;
    for (int i = t; i < NBUCK; i += 256) lb[i] = 0;
    __syncthreads();
    int base = blockIdx.x * EPB_A;
    #pragma unroll 4
    for (int k = 0; k < EPB_A / 256; ++k) {
        int e = base + k * 256 + t;
        if (e < ETOT) {
            int s, d; edge_sd(ei, e, s, d); (void)s;
            atomicAdd(&lb[d >> 6], 1);
        }
    }
    __syncthreads();
    for (int i = t; i < NBUCK; i += 256) {
        int c = lb[i];
        lb[i] = c ? atomicAdd(&bucket_cur[i], c) : 0;
    }
    __syncthreads();
    #pragma unroll 4
    for (int k = 0; k < EPB_A / 256; ++k) {
        int e = base + k * 256 + t;
        if (e < ETOT) {
            int s, d; edge_sd(ei, e, s, d);
            int pos = atomicAdd(&lb[d >> 6], 1);
            ebkt[pos] = ((unsigned)d << 16) | (unsigned)s;
        }
    }
}

// kB: per-bucket count + in-LDS scan + row_ptr write + within-bucket scatter (one kernel)
__global__ __launch_bounds__(256) void kB(const int* __restrict__ bucket_off,
                                          const unsigned* __restrict__ ebkt,
                                          int* __restrict__ row_ptr,
                                          int* __restrict__ src_sorted) {
    __shared__ int lc[64];
    int b = blockIdx.x, t = threadIdx.x;
    if (t < 64) lc[t] = 0;
    __syncthreads();
    int s0 = bucket_off[b], s1 = bucket_off[b + 1];
    for (int i = s0 + t; i < s1; i += 256) atomicAdd(&lc[(ebkt[i] >> 16) & 63], 1);
    __syncthreads();
    if (t < 64) {   // wave 0: inclusive shfl scan over 64 counters
        int v = lc[t];
        int inc = v;
        #pragma unroll
        for (int off = 1; off < 64; off <<= 1) {
            int u = __shfl_up(inc, off);
            if (t >= off) inc += u;
        }
        int ex = s0 + inc - v;
        row_ptr[b * 64 + t] = ex;
        lc[t] = ex;     // cursor
    }
    __syncthreads();
    for (int i = s0 + t; i < s1; i += 256) {
        unsigned k = ebkt[i];
        int pos = atomicAdd(&lc[(k >> 16) & 63], 1);
        src_sorted[pos] = (int)(k & 0xffffu);
    }
}

// ---------------- GEMM + attention coefficients (layers 0/1: 128 -> 8x16) ----------------
// 256 threads; 64 nodes x 128 cols per block; each thread 8 nodes x 4 cols.
#define FMA4(xc, wv, i) \
    acc[i][0] = fmaf(xc, wv.x, acc[i][0]); \
    acc[i][1] = fmaf(xc, wv.y, acc[i][1]); \
    acc[i][2] = fmaf(xc, wv.z, acc[i][2]); \
    acc[i][3] = fmaf(xc, wv.w, acc[i][3]);

__global__ __launch_bounds__(256) void gemm_att128(
    const float* __restrict__ x, const float* __restrict__ W,
    const float* __restrict__ asrc, const float* __restrict__ adst,
    unsigned* __restrict__ hb, float* __restrict__ als, float* __restrict__ ald)
{
    __shared__ float ws[32 * 128];   // [32k][128c] 16KB
    __shared__ float xs[64 * 32];    // [64n][32k]  8KB
    int t = threadIdx.x;
    int tx = t & 31, ty = t >> 5;    // cols 4tx..4tx+3 ; nodes ty*8..ty*8+7
    int n0 = blockIdx.x * 64;

    float acc[8][4];
    #pragma unroll
    for (int i = 0; i < 8; ++i)
        #pragma unroll
        for (int j = 0; j < 4; ++j) acc[i][j] = 0.f;

    for (int kt = 0; kt < 4; ++kt) {
        const float4* Wg = (const float4*)(W + (size_t)kt * 32 * 128);
        #pragma unroll
        for (int i = 0; i < 4; ++i) ((float4*)ws)[i * 256 + t] = Wg[i * 256 + t];
        #pragma unroll
        for (int q = 0; q < 2; ++q) {
            int idx = q * 256 + t;           // 0..511
            int n = idx >> 3, f4 = idx & 7;
            int ng = n0 + n; if (ng >= NN) ng = NN - 1;
            ((float4*)xs)[idx] = ((const float4*)(x + (size_t)ng * 128))[kt * 8 + f4];
        }
        __syncthreads();
        #pragma unroll
        for (int kc = 0; kc < 8; ++kc) {
            float4 wv0 = ((const float4*)(ws + (kc * 4 + 0) * 128))[tx];
            float4 wv1 = ((const float4*)(ws + (kc * 4 + 1) * 128))[tx];
            float4 wv2 = ((const float4*)(ws + (kc * 4 + 2) * 128))[tx];
            float4 wv3 = ((const float4*)(ws + (kc * 4 + 3) * 128))[tx];
            #pragma unroll
            for (int i = 0; i < 8; ++i) {
                float4 xv = ((const float4*)(xs + (ty * 8 + i) * 32))[kc];
                FMA4(xv.x, wv0, i)
                FMA4(xv.y, wv1, i)
                FMA4(xv.z, wv2, i)
                FMA4(xv.w, wv3, i)
            }
        }
        __syncthreads();
    }

    float4 as4 = ((const float4*)asrc)[tx];
    float4 ad4 = ((const float4*)adst)[tx];
    int hd = tx >> 2;
    #pragma unroll
    for (int i = 0; i < 8; ++i) {
        int n = n0 + ty * 8 + i;
        if (n < NN) {
            uint2 hp;
            hp.x = pack_bf16x2(acc[i][0], acc[i][1]);
            hp.y = pack_bf16x2(acc[i][2], acc[i][3]);
            ((uint2*)(hb + (size_t)n * 64))[tx] = hp;
            float v1 = acc[i][0] * as4.x + acc[i][1] * as4.y + acc[i][2] * as4.z + acc[i][3] * as4.w;
            float v2 = acc[i][0] * ad4.x + acc[i][1] * ad4.y + acc[i][2] * ad4.z + acc[i][3] * ad4.w;
            v1 += __shfl_xor(v1, 1); v1 += __shfl_xor(v1, 2);
            v2 += __shfl_xor(v2, 1); v2 += __shfl_xor(v2, 2);
            if ((tx & 3) == 0) { als[n * 8 + hd] = v1; ald[n * 8 + hd] = v2; }
        }
    }
}

// ---------------- GEMM + attention (layer 2: 128 -> 1x40, bf16-packed output) ----------------
__global__ __launch_bounds__(256) void gemm_att40(
    const float* __restrict__ x, const float* __restrict__ W,
    const float* __restrict__ asrc, const float* __restrict__ adst,
    unsigned* __restrict__ hb40, float* __restrict__ als, float* __restrict__ ald)
{
    __shared__ float ws[128 * 40];
    __shared__ float xs[16 * 128];
    int t = threadIdx.x;
    int n0 = blockIdx.x * 16;
    #pragma unroll
    for (int i = 0; i < 5; ++i) ((float4*)ws)[i * 256 + t] = ((const float4*)W)[i * 256 + t];
    #pragma unroll
    for (int q = 0; q < 2; ++q) {
        int idx = q * 256 + t;
        int n = idx >> 5, kc = idx & 31;
        ((float4*)xs)[idx] = ((const float4*)(x + (size_t)(n0 + n) * 128))[kc];
    }
    __syncthreads();
    int w = t >> 6, c = t & 63;
    int cc = c < 40 ? c : 39;
    float acc[4] = {0.f, 0.f, 0.f, 0.f};
    #pragma unroll 4
    for (int kc = 0; kc < 32; ++kc) {
        float w0 = ws[(kc * 4 + 0) * 40 + cc];
        float w1 = ws[(kc * 4 + 1) * 40 + cc];
        float w2 = ws[(kc * 4 + 2) * 40 + cc];
        float w3 = ws[(kc * 4 + 3) * 40 + cc];
        #pragma unroll
        for (int i = 0; i < 4; ++i) {
            float4 xv = ((const float4*)(xs + (4 * w + i) * 128))[kc];
            acc[i] = fmaf(xv.x, w0, acc[i]);
            acc[i] = fmaf(xv.y, w1, acc[i]);
            acc[i] = fmaf(xv.z, w2, acc[i]);
            acc[i] = fmaf(xv.w, w3, acc[i]);
        }
    }
    float a_s = (c < 40) ? asrc[c] : 0.f;
    float a_d = (c < 40) ? adst[c] : 0.f;
    #pragma unroll
    for (int i = 0; i < 4; ++i) {
        int n = n0 + 4 * w + i;
        float nb = __shfl_xor(acc[i], 1);
        if ((c & 1) == 0 && c < 40) hb40[(size_t)n * 32 + (c >> 1)] = pack_bf16x2(acc[i], nb);
        float v1 = acc[i] * a_s, v2 = acc[i] * a_d;
        #pragma unroll
        for (int m = 1; m < 64; m <<= 1) { v1 += __shfl_xor(v1, m); v2 += __shfl_xor(v2, m); }
        if (c == 0) { als[n] = v1; ald[n] = v2; }
    }
}

// ---------------- fused single-pass softmax + aggregate + finalize ----------------
// Chunk-of-8 edges: lane j computes alpha ONCE for (slot j>>3, head j&7); feature lanes
// pull it via shuffle. Removes the 8x-redundant exp/als-load of the per-edge version.
template<bool RELU>
__global__ void dst_agg128(const int* __restrict__ row_ptr, const int* __restrict__ src_sorted,
                           const float* __restrict__ als, const float* __restrict__ ald,
                           const unsigned* __restrict__ hb, const float* __restrict__ bias,
                           float* __restrict__ out)
{
    int w = (blockIdx.x * blockDim.x + threadIdx.x) >> 6;
    if (w >= NN) return;
    int j = threadIdx.x & 63;
    int myh = j >> 3;           // feature-role head (features 2j, 2j+1)
    int ah = j & 7;             // alpha-role head
    int aslot = j >> 3;         // alpha-role edge slot
    float aldv = ald[w * 8 + ah];
    int start = row_ptr[w], end = row_ptr[w + 1];
    float2 acc = make_float2(0.f, 0.f);
    float denp = 0.f;
    int i = start;
    for (; i + 8 <= end; i += 8) {
        int sa = src_sorted[i + aslot];
        float e = als[sa * 8 + ah] + aldv;
        e = e > 0.f ? e : 0.2f * e;
        float a = __expf(e);
        denp += a;
        #pragma unroll
        for (int k = 0; k < 8; ++k) {
            float ak = __shfl(a, k * 8 + myh);
            int sk = __shfl(sa, k * 8);                 // wave-uniform
            float2 hv = unpack_bf16x2(hb[(size_t)sk * 64 + j]);
            acc.x = fmaf(hv.x, ak, acc.x);
            acc.y = fmaf(hv.y, ak, acc.y);
        }
    }
    // reduce chunked den over slots (same ah across xor 8/16/32), map to my head
    denp += __shfl_xor(denp, 8);
    denp += __shfl_xor(denp, 16);
    denp += __shfl_xor(denp, 32);
    float den = __shfl(denp, myh);
    float ald_my = __shfl(aldv, myh);
    // tail (<8 edges): per-edge, alpha computed per feature lane
    for (; i < end; ++i) {
        int s0 = src_sorted[i];
        float e0 = als[s0 * 8 + myh] + ald_my;
        e0 = e0 > 0.f ? e0 : 0.2f * e0;
        float a0 = __expf(e0);
        den += a0;
        float2 h0 = unpack_bf16x2(hb[(size_t)s0 * 64 + j]);
        acc.x = fmaf(h0.x, a0, acc.x);
        acc.y = fmaf(h0.y, a0, acc.y);
    }
    float inv = 1.f / (den + 1e-16f);
    float2 bv = ((const float2*)bias)[j];
    float2 o;
    o.x = acc.x * inv + bv.x;
    o.y = acc.y * inv + bv.y;
    if (RELU) { o.x = fmaxf(o.x, 0.f); o.y = fmaxf(o.y, 0.f); }
    ((float2*)out)[(size_t)w * 64 + j] = o;
}

// H=1: lane j<20 owns features 2j,2j+1 (bf16-packed h40, 128B row stride)
__global__ void dst_agg40(const int* __restrict__ row_ptr, const int* __restrict__ src_sorted,
                          const float* __restrict__ als, const float* __restrict__ ald,
                          const unsigned* __restrict__ hb40, const float* __restrict__ bias,
                          float* __restrict__ out)
{
    int w = (blockIdx.x * blockDim.x + threadIdx.x) >> 6;
    if (w >= NN) return;
    int j = threadIdx.x & 63;
    int aslot = j >> 3;
    float aldv = ald[w];
    int start = row_ptr[w], end = row_ptr[w + 1];
    float2 acc = make_float2(0.f, 0.f);
    float denp = 0.f;
    int i = start;
    for (; i + 8 <= end; i += 8) {
        int sa = src_sorted[i + aslot];
        float e = als[sa] + aldv;
        e = e > 0.f ? e : 0.2f * e;
        float a = __expf(e);
        denp += a;
        #pragma unroll
        for (int k = 0; k < 8; ++k) {
            float ak = __shfl(a, k * 8);
            int sk = __shfl(sa, k * 8);
            if (j < 20) {
                float2 hv = unpack_bf16x2(hb40[(size_t)sk * 32 + j]);
                acc.x = fmaf(hv.x, ak, acc.x);
                acc.y = fmaf(hv.y, ak, acc.y);
            }
        }
    }
    denp += __shfl_xor(denp, 8);
    denp += __shfl_xor(denp, 16);
    denp += __shfl_xor(denp, 32);
    float den = denp;
    for (; i < end; ++i) {
        int s0 = src_sorted[i];
        float e0 = als[s0] + aldv;
        e0 = e0 > 0.f ? e0 : 0.2f * e0;
        float a0 = __expf(e0);
        den += a0;
        if (j < 20) {
            float2 hv = unpack_bf16x2(hb40[(size_t)s0 * 32 + j]);
            acc.x = fmaf(hv.x, a0, acc.x);
            acc.y = fmaf(hv.y, a0, acc.y);
        }
    }
    if (j < 20) {
        float inv = 1.f / (den + 1e-16f);
        out[(size_t)w * 40 + 2 * j]     = acc.x * inv + bias[2 * j];
        out[(size_t)w * 40 + 2 * j + 1] = acc.y * inv + bias[2 * j + 1];
    }
}

extern "C" void kernel_launch(void* const* d_in, const int* in_sizes, int n_in,
                              void* d_out, int out_size, void* d_ws, size_t ws_size,
                              hipStream_t stream) {
    const float* x   = (const float*)d_in[0];
    const int*   ei  = (const int*)d_in[1];
    const float* W0  = (const float*)d_in[2];
    const float* as0 = (const float*)d_in[3];
    const float* ad0 = (const float*)d_in[4];
    const float* b0  = (const float*)d_in[5];
    const float* W1  = (const float*)d_in[6];
    const float* as1 = (const float*)d_in[7];
    const float* ad1 = (const float*)d_in[8];
    const float* b1  = (const float*)d_in[9];
    const float* W2  = (const float*)d_in[10];
    const float* as2 = (const float*)d_in[11];
    const float* ad2 = (const float*)d_in[12];
    const float* b2  = (const float*)d_in[13];
    float* out = (float*)d_out;

    float* ws = (float*)d_ws;
    size_t off = 0;
    unsigned* hb   = (unsigned*)(ws + off); off += (size_t)NN * 64;  // bf16 h, layers 0/1
    float* fA      = ws + off; off += (size_t)NN * 128;
    float* fB      = ws + off; off += (size_t)NN * 128;
    unsigned* hb40 = (unsigned*)(ws + off); off += (size_t)NN * 32;  // bf16 h, layer 2
    float* als     = ws + off; off += (size_t)NN * 8;
    float* ald     = ws + off; off += (size_t)NN * 8;
    int* ibase       = (int*)(ws + off);
    int* bucket_cnt  = ibase; ibase += NBUCK;
    int* bucket_off  = ibase; ibase += NBUCK + 2;
    int* bucket_cur  = ibase; ibase += NBUCK;
    int* row_ptr     = ibase; ibase += NCNT + 1;
    unsigned* ebkt   = (unsigned*)ibase; ibase += ETOT;
    int* src_sorted  = ibase; ibase += ETOT;

    const int TB = 256;

    // ---- CSR build (bucketed counting sort; shared by all 3 layers) ----
    hipMemsetAsync(bucket_cnt, 0, NBUCK * sizeof(int), stream);
    kA1<<<NBLK_A, 256, 0, stream>>>(ei, bucket_cnt);
    kA2<<<1, 1024, 0, stream>>>(bucket_cnt, bucket_off, bucket_cur);
    kA3<<<NBLK_A, 256, 0, stream>>>(ei, bucket_cur, ebkt);
    kB<<<NBUCK, 256, 0, stream>>>(bucket_off, ebkt, row_ptr, src_sorted);

    const int GG128 = (NN + 63) / 64;               // 782
    const int GG40  = NN / 16;                      // 3125 (exact)
    const int GAGG  = (NN * 64 + TB - 1) / TB;      // one wave per node

    // ---- Layer 0 ----
    gemm_att128<<<GG128, 256, 0, stream>>>(x, W0, as0, ad0, hb, als, ald);
    dst_agg128<true><<<GAGG, TB, 0, stream>>>(row_ptr, src_sorted, als, ald, hb, b0, fA);

    // ---- Layer 1 ----
    gemm_att128<<<GG128, 256, 0, stream>>>(fA, W1, as1, ad1, hb, als, ald);
    dst_agg128<true><<<GAGG, TB, 0, stream>>>(row_ptr, src_sorted, als, ald, hb, b1, fB);

    // ---- Layer 2 ----
    gemm_att40<<<GG40, 256, 0, stream>>>(fB, W2, as2, ad2, hb40, als, ald);
    dst_agg40<<<GAGG, TB, 0, stream>>>(row_ptr, src_sorted, als, ald, hb40, b2, out);
}

// Round 8
// 270.736 us; speedup vs baseline: 1.1743x; 1.1743x over previous
//
#include <hip/hip_runtime.h>

#define NN    50000
#define ERAW  800000
#define ETOT  850000
#define NBUCK 782            // ceil(NN/64) buckets of 64 dst nodes
#define EPB_A 8192           // edges per block in bucketing passes
#define NBLK_A ((ETOT + EPB_A - 1) / EPB_A)   // 104
#define NCNT  (NBUCK * 64)   // 50048 (padded per-dst count array)

__device__ __forceinline__ void edge_sd(const int* __restrict__ ei, int e, int& s, int& d) {
    if (e < ERAW) { s = ei[e]; d = ei[ERAW + e]; }
    else { int n = e - ERAW; s = n; d = n; }
}

// bf16 pack/unpack (RNE), 2 elements per uint: low16 = a, high16 = b
__device__ __forceinline__ unsigned pack_bf16x2(float a, float b) {
    unsigned ua = __float_as_uint(a), ub = __float_as_uint(b);
    ua += 0x7fffu + ((ua >> 16) & 1u);
    ub += 0x7fffu + ((ub >> 16) & 1u);
    return (ua >> 16) | (ub & 0xffff0000u);
}
__device__ __forceinline__ float2 unpack_bf16x2(unsigned v) {
    float2 r;
    r.x = __uint_as_float(v << 16);
    r.y = __uint_as_float(v & 0xffff0000u);
    return r;
}

// ---------------- CSR build: two-level bucketed counting sort ----------------
__global__ __launch_bounds__(256) void kA1(const int* __restrict__ ei, int* __restrict__ bucket_cnt) {
    __shared__ int lb[NBUCK];
    int t = threadIdx.x;
    for (int i = t; i < NBUCK; i += 256) lb[i] = 0;
    __syncthreads();
    int base = blockIdx.x * EPB_A;
    #pragma unroll 4
    for (int k = 0; k < EPB_A / 256; ++k) {
        int e = base + k * 256 + t;
        if (e < ETOT) {
            int s, d; edge_sd(ei, e, s, d); (void)s;
            atomicAdd(&lb[d >> 6], 1);
        }
    }
    __syncthreads();
    for (int i = t; i < NBUCK; i += 256) if (lb[i]) atomicAdd(&bucket_cnt[i], lb[i]);
}

__global__ void kA2(const int* __restrict__ bucket_cnt, int* __restrict__ bucket_off,
                    int* __restrict__ bucket_cur) {
    __shared__ int tmp[1024];
    int t = threadIdx.x;
    int v = (t < NBUCK) ? bucket_cnt[t] : 0;
    tmp[t] = v;
    __syncthreads();
    for (int off = 1; off < 1024; off <<= 1) {
        int u = (t >= off) ? tmp[t - off] : 0;
        __syncthreads();
        tmp[t] += u;
        __syncthreads();
    }
    if (t < NBUCK) { int ex = tmp[t] - v; bucket_off[t] = ex; bucket_cur[t] = ex; }
    if (t == 0) bucket_off[NBUCK] = ETOT;
}

__global__ __launch_bounds__(256) void kA3(const int* __restrict__ ei, int* __restrict__ bucket_cur,
                                           unsigned* __restrict__ ebkt) {
    __shared__ int lb[NBUCK];
    int t = threadIdx.x;
    for (int i = t; i < NBUCK; i += 256) lb[i] = 0;
    __syncthreads();
    int base = blockIdx.x * EPB_A;
    #pragma unroll 4
    for (int k = 0; k < EPB_A / 256; ++k) {
        int e = base + k * 256 + t;
        if (e < ETOT) {
            int s, d; edge_sd(ei, e, s, d); (void)s;
            atomicAdd(&lb[d >> 6], 1);
        }
    }
    __syncthreads();
    for (int i = t; i < NBUCK; i += 256) {
        int c = lb[i];
        lb[i] = c ? atomicAdd(&bucket_cur[i], c) : 0;
    }
    __syncthreads();
    #pragma unroll 4
    for (int k = 0; k < EPB_A / 256; ++k) {
        int e = base + k * 256 + t;
        if (e < ETOT) {
            int s, d; edge_sd(ei, e, s, d);
            int pos = atomicAdd(&lb[d >> 6], 1);
            ebkt[pos] = ((unsigned)d << 16) | (unsigned)s;
        }
    }
}

// kB: per-bucket count + in-LDS scan + row_ptr write + within-bucket scatter
__global__ __launch_bounds__(256) void kB(const int* __restrict__ bucket_off,
                                          const unsigned* __restrict__ ebkt,
                                          int* __restrict__ row_ptr,
                                          int* __restrict__ src_sorted) {
    __shared__ int lc[64];
    int b = blockIdx.x, t = threadIdx.x;
    if (t < 64) lc[t] = 0;
    __syncthreads();
    int s0 = bucket_off[b], s1 = bucket_off[b + 1];
    for (int i = s0 + t; i < s1; i += 256) atomicAdd(&lc[(ebkt[i] >> 16) & 63], 1);
    __syncthreads();
    if (t < 64) {
        int v = lc[t];
        int inc = v;
        #pragma unroll
        for (int off = 1; off < 64; off <<= 1) {
            int u = __shfl_up(inc, off);
            if (t >= off) inc += u;
        }
        int ex = s0 + inc - v;
        row_ptr[b * 64 + t] = ex;
        lc[t] = ex;
    }
    __syncthreads();
    for (int i = s0 + t; i < s1; i += 256) {
        unsigned k = ebkt[i];
        int pos = atomicAdd(&lc[(k >> 16) & 63], 1);
        src_sorted[pos] = (int)(k & 0xffffu);
    }
}

// ---------------- GEMM + attention coefficients (layers 0/1: 128 -> 8x16) ----------------
// 256 threads; 64 nodes x 128 cols per block; each thread 8 nodes x 4 cols.
#define FMA4(xc, wv, i) \
    acc[i][0] = fmaf(xc, wv.x, acc[i][0]); \
    acc[i][1] = fmaf(xc, wv.y, acc[i][1]); \
    acc[i][2] = fmaf(xc, wv.z, acc[i][2]); \
    acc[i][3] = fmaf(xc, wv.w, acc[i][3]);

__global__ __launch_bounds__(256) void gemm_att128(
    const float* __restrict__ x, const float* __restrict__ W,
    const float* __restrict__ asrc, const float* __restrict__ adst,
    unsigned* __restrict__ hb, float* __restrict__ als, float* __restrict__ ald)
{
    __shared__ float ws[32 * 128];   // [32k][128c] 16KB
    __shared__ float xs[64 * 32];    // [64n][32k]  8KB
    int t = threadIdx.x;
    int tx = t & 31, ty = t >> 5;    // cols 4tx..4tx+3 ; nodes ty*8..ty*8+7
    int n0 = blockIdx.x * 64;

    float acc[8][4];
    #pragma unroll
    for (int i = 0; i < 8; ++i)
        #pragma unroll
        for (int j = 0; j < 4; ++j) acc[i][j] = 0.f;

    for (int kt = 0; kt < 4; ++kt) {
        const float4* Wg = (const float4*)(W + (size_t)kt * 32 * 128);
        #pragma unroll
        for (int i = 0; i < 4; ++i) ((float4*)ws)[i * 256 + t] = Wg[i * 256 + t];
        #pragma unroll
        for (int q = 0; q < 2; ++q) {
            int idx = q * 256 + t;
            int n = idx >> 3, f4 = idx & 7;
            int ng = n0 + n; if (ng >= NN) ng = NN - 1;
            ((float4*)xs)[idx] = ((const float4*)(x + (size_t)ng * 128))[kt * 8 + f4];
        }
        __syncthreads();
        #pragma unroll
        for (int kc = 0; kc < 8; ++kc) {
            float4 wv0 = ((const float4*)(ws + (kc * 4 + 0) * 128))[tx];
            float4 wv1 = ((const float4*)(ws + (kc * 4 + 1) * 128))[tx];
            float4 wv2 = ((const float4*)(ws + (kc * 4 + 2) * 128))[tx];
            float4 wv3 = ((const float4*)(ws + (kc * 4 + 3) * 128))[tx];
            #pragma unroll
            for (int i = 0; i < 8; ++i) {
                float4 xv = ((const float4*)(xs + (ty * 8 + i) * 32))[kc];
                FMA4(xv.x, wv0, i)
                FMA4(xv.y, wv1, i)
                FMA4(xv.z, wv2, i)
                FMA4(xv.w, wv3, i)
            }
        }
        __syncthreads();
    }

    float4 as4 = ((const float4*)asrc)[tx];
    float4 ad4 = ((const float4*)adst)[tx];
    int hd = tx >> 2;
    #pragma unroll
    for (int i = 0; i < 8; ++i) {
        int n = n0 + ty * 8 + i;
        if (n < NN) {
            uint2 hp;
            hp.x = pack_bf16x2(acc[i][0], acc[i][1]);
            hp.y = pack_bf16x2(acc[i][2], acc[i][3]);
            ((uint2*)(hb + (size_t)n * 64))[tx] = hp;
            float v1 = acc[i][0] * as4.x + acc[i][1] * as4.y + acc[i][2] * as4.z + acc[i][3] * as4.w;
            float v2 = acc[i][0] * ad4.x + acc[i][1] * ad4.y + acc[i][2] * ad4.z + acc[i][3] * ad4.w;
            v1 += __shfl_xor(v1, 1); v1 += __shfl_xor(v1, 2);
            v2 += __shfl_xor(v2, 1); v2 += __shfl_xor(v2, 2);
            if ((tx & 3) == 0) { als[n * 8 + hd] = v1; ald[n * 8 + hd] = v2; }
        }
    }
}

// ---------------- GEMM + attention (layer 2: 128 -> 1x40, bf16-packed output) ----------------
__global__ __launch_bounds__(256) void gemm_att40(
    const float* __restrict__ x, const float* __restrict__ W,
    const float* __restrict__ asrc, const float* __restrict__ adst,
    unsigned* __restrict__ hb40, float* __restrict__ als, float* __restrict__ ald)
{
    __shared__ float ws[128 * 40];
    __shared__ float xs[16 * 128];
    int t = threadIdx.x;
    int n0 = blockIdx.x * 16;
    #pragma unroll
    for (int i = 0; i < 5; ++i) ((float4*)ws)[i * 256 + t] = ((const float4*)W)[i * 256 + t];
    #pragma unroll
    for (int q = 0; q < 2; ++q) {
        int idx = q * 256 + t;
        int n = idx >> 5, kc = idx & 31;
        ((float4*)xs)[idx] = ((const float4*)(x + (size_t)(n0 + n) * 128))[kc];
    }
    __syncthreads();
    int w = t >> 6, c = t & 63;
    int cc = c < 40 ? c : 39;
    float acc[4] = {0.f, 0.f, 0.f, 0.f};
    #pragma unroll 4
    for (int kc = 0; kc < 32; ++kc) {
        float w0 = ws[(kc * 4 + 0) * 40 + cc];
        float w1 = ws[(kc * 4 + 1) * 40 + cc];
        float w2 = ws[(kc * 4 + 2) * 40 + cc];
        float w3 = ws[(kc * 4 + 3) * 40 + cc];
        #pragma unroll
        for (int i = 0; i < 4; ++i) {
            float4 xv = ((const float4*)(xs + (4 * w + i) * 128))[kc];
            acc[i] = fmaf(xv.x, w0, acc[i]);
            acc[i] = fmaf(xv.y, w1, acc[i]);
            acc[i] = fmaf(xv.z, w2, acc[i]);
            acc[i] = fmaf(xv.w, w3, acc[i]);
        }
    }
    float a_s = (c < 40) ? asrc[c] : 0.f;
    float a_d = (c < 40) ? adst[c] : 0.f;
    #pragma unroll
    for (int i = 0; i < 4; ++i) {
        int n = n0 + 4 * w + i;
        float nb = __shfl_xor(acc[i], 1);
        if ((c & 1) == 0 && c < 40) hb40[(size_t)n * 32 + (c >> 1)] = pack_bf16x2(acc[i], nb);
        float v1 = acc[i] * a_s, v2 = acc[i] * a_d;
        #pragma unroll
        for (int m = 1; m < 64; m <<= 1) { v1 += __shfl_xor(v1, m); v2 += __shfl_xor(v2, m); }
        if (c == 0) { als[n] = v1; ald[n] = v2; }
    }
}

// ---------------- fused single-pass softmax + aggregate + finalize (bf16 h gather) ----------------
// Per-edge unroll-4 (max MLP). Redundant per-lane alpha is issue-free in SIMT.
template<bool RELU>
__global__ void dst_agg128(const int* __restrict__ row_ptr, const int* __restrict__ src_sorted,
                           const float* __restrict__ als, const float* __restrict__ ald,
                           const unsigned* __restrict__ hb, const float* __restrict__ bias,
                           float* __restrict__ out)
{
    int w = (blockIdx.x * blockDim.x + threadIdx.x) >> 6;
    if (w >= NN) return;
    int j = threadIdx.x & 63;
    int myh = j >> 3;
    float aldv = ald[w * 8 + myh];
    int start = row_ptr[w], end = row_ptr[w + 1];
    float2 acc = make_float2(0.f, 0.f);
    float den = 0.f;
    int i = start;
    for (; i + 4 <= end; i += 4) {
        int s0 = src_sorted[i], s1 = src_sorted[i + 1], s2 = src_sorted[i + 2], s3 = src_sorted[i + 3];
        float e0 = als[s0 * 8 + myh] + aldv;
        float e1 = als[s1 * 8 + myh] + aldv;
        float e2 = als[s2 * 8 + myh] + aldv;
        float e3 = als[s3 * 8 + myh] + aldv;
        unsigned p0 = hb[(size_t)s0 * 64 + j];
        unsigned p1 = hb[(size_t)s1 * 64 + j];
        unsigned p2 = hb[(size_t)s2 * 64 + j];
        unsigned p3 = hb[(size_t)s3 * 64 + j];
        e0 = e0 > 0.f ? e0 : 0.2f * e0;
        e1 = e1 > 0.f ? e1 : 0.2f * e1;
        e2 = e2 > 0.f ? e2 : 0.2f * e2;
        e3 = e3 > 0.f ? e3 : 0.2f * e3;
        float a0 = __expf(e0), a1 = __expf(e1), a2 = __expf(e2), a3 = __expf(e3);
        den += (a0 + a1) + (a2 + a3);
        float2 h0 = unpack_bf16x2(p0), h1 = unpack_bf16x2(p1);
        float2 h2 = unpack_bf16x2(p2), h3 = unpack_bf16x2(p3);
        acc.x = fmaf(h0.x, a0, acc.x); acc.y = fmaf(h0.y, a0, acc.y);
        acc.x = fmaf(h1.x, a1, acc.x); acc.y = fmaf(h1.y, a1, acc.y);
        acc.x = fmaf(h2.x, a2, acc.x); acc.y = fmaf(h2.y, a2, acc.y);
        acc.x = fmaf(h3.x, a3, acc.x); acc.y = fmaf(h3.y, a3, acc.y);
    }
    for (; i < end; ++i) {
        int s0 = src_sorted[i];
        float e0 = als[s0 * 8 + myh] + aldv;
        e0 = e0 > 0.f ? e0 : 0.2f * e0;
        float a0 = __expf(e0);
        den += a0;
        float2 h0 = unpack_bf16x2(hb[(size_t)s0 * 64 + j]);
        acc.x = fmaf(h0.x, a0, acc.x);
        acc.y = fmaf(h0.y, a0, acc.y);
    }
    float inv = 1.f / (den + 1e-16f);
    float2 bv = ((const float2*)bias)[j];
    float2 o;
    o.x = acc.x * inv + bv.x;
    o.y = acc.y * inv + bv.y;
    if (RELU) { o.x = fmaxf(o.x, 0.f); o.y = fmaxf(o.y, 0.f); }
    ((float2*)out)[(size_t)w * 64 + j] = o;
}

// H=1, C=40: TWO nodes per wave (lanes 0-31 -> node 2wp, 32-63 -> node 2wp+1).
// Within a half, lanes 0-19 own packed feature pairs; alpha redundant per lane (free).
__global__ void dst_agg40(const int* __restrict__ row_ptr, const int* __restrict__ src_sorted,
                          const float* __restrict__ als, const float* __restrict__ ald,
                          const unsigned* __restrict__ hb40, const float* __restrict__ bias,
                          float* __restrict__ out)
{
    int wp = (blockIdx.x * blockDim.x + threadIdx.x) >> 6;
    if (wp >= NN / 2) return;
    int lane = threadIdx.x & 63;
    int half = lane >> 5, l = lane & 31;
    int node = 2 * wp + half;
    float aldv = ald[node];
    int i = row_ptr[node], end = row_ptr[node + 1];
    float2 acc = make_float2(0.f, 0.f);
    float den = 0.f;
    for (; i + 4 <= end; i += 4) {
        int s0 = src_sorted[i], s1 = src_sorted[i + 1], s2 = src_sorted[i + 2], s3 = src_sorted[i + 3];
        float e0 = als[s0] + aldv;
        float e1 = als[s1] + aldv;
        float e2 = als[s2] + aldv;
        float e3 = als[s3] + aldv;
        unsigned p0 = 0, p1 = 0, p2 = 0, p3 = 0;
        if (l < 20) {
            p0 = hb40[(size_t)s0 * 32 + l];
            p1 = hb40[(size_t)s1 * 32 + l];
            p2 = hb40[(size_t)s2 * 32 + l];
            p3 = hb40[(size_t)s3 * 32 + l];
        }
        e0 = e0 > 0.f ? e0 : 0.2f * e0;
        e1 = e1 > 0.f ? e1 : 0.2f * e1;
        e2 = e2 > 0.f ? e2 : 0.2f * e2;
        e3 = e3 > 0.f ? e3 : 0.2f * e3;
        float a0 = __expf(e0), a1 = __expf(e1), a2 = __expf(e2), a3 = __expf(e3);
        den += (a0 + a1) + (a2 + a3);
        float2 h0 = unpack_bf16x2(p0), h1 = unpack_bf16x2(p1);
        float2 h2 = unpack_bf16x2(p2), h3 = unpack_bf16x2(p3);
        acc.x = fmaf(h0.x, a0, acc.x); acc.y = fmaf(h0.y, a0, acc.y);
        acc.x = fmaf(h1.x, a1, acc.x); acc.y = fmaf(h1.y, a1, acc.y);
        acc.x = fmaf(h2.x, a2, acc.x); acc.y = fmaf(h2.y, a2, acc.y);
        acc.x = fmaf(h3.x, a3, acc.x); acc.y = fmaf(h3.y, a3, acc.y);
    }
    for (; i < end; ++i) {
        int s0 = src_sorted[i];
        float e0 = als[s0] + aldv;
        e0 = e0 > 0.f ? e0 : 0.2f * e0;
        float a0 = __expf(e0);
        den += a0;
        if (l < 20) {
            float2 hv = unpack_bf16x2(hb40[(size_t)s0 * 32 + l]);
            acc.x = fmaf(hv.x, a0, acc.x);
            acc.y = fmaf(hv.y, a0, acc.y);
        }
    }
    if (l < 20) {
        float inv = 1.f / (den + 1e-16f);
        float2 o;
        o.x = acc.x * inv + bias[2 * l];
        o.y = acc.y * inv + bias[2 * l + 1];
        ((float2*)(out + (size_t)node * 40))[l] = o;
    }
}

extern "C" void kernel_launch(void* const* d_in, const int* in_sizes, int n_in,
                              void* d_out, int out_size, void* d_ws, size_t ws_size,
                              hipStream_t stream) {
    const float* x   = (const float*)d_in[0];
    const int*   ei  = (const int*)d_in[1];
    const float* W0  = (const float*)d_in[2];
    const float* as0 = (const float*)d_in[3];
    const float* ad0 = (const float*)d_in[4];
    const float* b0  = (const float*)d_in[5];
    const float* W1  = (const float*)d_in[6];
    const float* as1 = (const float*)d_in[7];
    const float* ad1 = (const float*)d_in[8];
    const float* b1  = (const float*)d_in[9];
    const float* W2  = (const float*)d_in[10];
    const float* as2 = (const float*)d_in[11];
    const float* ad2 = (const float*)d_in[12];
    const float* b2  = (const float*)d_in[13];
    float* out = (float*)d_out;

    float* ws = (float*)d_ws;
    size_t off = 0;
    unsigned* hb   = (unsigned*)(ws + off); off += (size_t)NN * 64;  // bf16 h, layers 0/1
    float* fA      = ws + off; off += (size_t)NN * 128;
    float* fB      = ws + off; off += (size_t)NN * 128;
    unsigned* hb40 = (unsigned*)(ws + off); off += (size_t)NN * 32;  // bf16 h, layer 2
    float* als     = ws + off; off += (size_t)NN * 8;
    float* ald     = ws + off; off += (size_t)NN * 8;
    int* ibase       = (int*)(ws + off);
    int* bucket_cnt  = ibase; ibase += NBUCK;
    int* bucket_off  = ibase; ibase += NBUCK + 2;
    int* bucket_cur  = ibase; ibase += NBUCK;
    int* row_ptr     = ibase; ibase += NCNT + 1;
    unsigned* ebkt   = (unsigned*)ibase; ibase += ETOT;
    int* src_sorted  = ibase; ibase += ETOT;

    const int TB = 256;

    // ---- CSR build (bucketed counting sort; shared by all 3 layers) ----
    hipMemsetAsync(bucket_cnt, 0, NBUCK * sizeof(int), stream);
    kA1<<<NBLK_A, 256, 0, stream>>>(ei, bucket_cnt);
    kA2<<<1, 1024, 0, stream>>>(bucket_cnt, bucket_off, bucket_cur);
    kA3<<<NBLK_A, 256, 0, stream>>>(ei, bucket_cur, ebkt);
    kB<<<NBUCK, 256, 0, stream>>>(bucket_off, ebkt, row_ptr, src_sorted);

    const int GG128 = (NN + 63) / 64;               // 782
    const int GG40  = NN / 16;                      // 3125 (exact)
    const int GAGG  = (NN * 64 + TB - 1) / TB;      // one wave per node
    const int GAGG2 = ((NN / 2) * 64 + TB - 1) / TB; // two nodes per wave

    // ---- Layer 0 ----
    gemm_att128<<<GG128, 256, 0, stream>>>(x, W0, as0, ad0, hb, als, ald);
    dst_agg128<true><<<GAGG, TB, 0, stream>>>(row_ptr, src_sorted, als, ald, hb, b0, fA);

    // ---- Layer 1 ----
    gemm_att128<<<GG128, 256, 0, stream>>>(fA, W1, as1, ad1, hb, als, ald);
    dst_agg128<true><<<GAGG, TB, 0, stream>>>(row_ptr, src_sorted, als, ald, hb, b1, fB);

    // ---- Layer 2 ----
    gemm_att40<<<GG40, 256, 0, stream>>>(fB, W2, as2, ad2, hb40, als, ald);
    dst_agg40<<<GAGG2, TB, 0, stream>>>(row_ptr, src_sorted, als, ald, hb40, b2, out);
}

// Round 9
// 247.219 us; speedup vs baseline: 1.2860x; 1.0951x over previous
//
#include <hip/hip_runtime.h>

#define NN    50000
#define ERAW  800000
#define ETOT  850000
#define NBUCK 782            // ceil(NN/64) buckets of 64 dst nodes
#define EPB_A 4096           // edges per block in bucketing passes
#define NBLK_A ((ETOT + EPB_A - 1) / EPB_A)   // 208
#define NCNT  (NBUCK * 64)   // 50048 (padded per-dst count array)

__device__ __forceinline__ void edge_sd(const int* __restrict__ ei, int e, int& s, int& d) {
    if (e < ERAW) { s = ei[e]; d = ei[ERAW + e]; }
    else { int n = e - ERAW; s = n; d = n; }
}

// bf16 pack/unpack (RNE), 2 elements per uint: low16 = a, high16 = b
__device__ __forceinline__ unsigned pack_bf16x2(float a, float b) {
    unsigned ua = __float_as_uint(a), ub = __float_as_uint(b);
    ua += 0x7fffu + ((ua >> 16) & 1u);
    ub += 0x7fffu + ((ub >> 16) & 1u);
    return (ua >> 16) | (ub & 0xffff0000u);
}
__device__ __forceinline__ float2 unpack_bf16x2(unsigned v) {
    float2 r;
    r.x = __uint_as_float(v << 16);
    r.y = __uint_as_float(v & 0xffff0000u);
    return r;
}

// ---------------- CSR build: two-level bucketed counting sort ----------------
__global__ __launch_bounds__(256) void kA1(const int* __restrict__ ei, int* __restrict__ bucket_cnt) {
    __shared__ int lb[NBUCK];
    int t = threadIdx.x;
    for (int i = t; i < NBUCK; i += 256) lb[i] = 0;
    __syncthreads();
    int base = blockIdx.x * EPB_A;
    #pragma unroll 4
    for (int k = 0; k < EPB_A / 256; ++k) {
        int e = base + k * 256 + t;
        if (e < ETOT) {
            int s, d; edge_sd(ei, e, s, d); (void)s;
            atomicAdd(&lb[d >> 6], 1);
        }
    }
    __syncthreads();
    for (int i = t; i < NBUCK; i += 256) if (lb[i]) atomicAdd(&bucket_cnt[i], lb[i]);
}

__global__ void kA2(const int* __restrict__ bucket_cnt, int* __restrict__ bucket_off,
                    int* __restrict__ bucket_cur) {
    __shared__ int tmp[1024];
    int t = threadIdx.x;
    int v = (t < NBUCK) ? bucket_cnt[t] : 0;
    tmp[t] = v;
    __syncthreads();
    for (int off = 1; off < 1024; off <<= 1) {
        int u = (t >= off) ? tmp[t - off] : 0;
        __syncthreads();
        tmp[t] += u;
        __syncthreads();
    }
    if (t < NBUCK) { int ex = tmp[t] - v; bucket_off[t] = ex; bucket_cur[t] = ex; }
    if (t == 0) bucket_off[NBUCK] = ETOT;
}

__global__ __launch_bounds__(256) void kA3(const int* __restrict__ ei, int* __restrict__ bucket_cur,
                                           unsigned* __restrict__ ebkt) {
    __shared__ int lb[NBUCK];
    int t = threadIdx.x;
    for (int i = t; i < NBUCK; i += 256) lb[i] = 0;
    __syncthreads();
    int base = blockIdx.x * EPB_A;
    #pragma unroll 4
    for (int k = 0; k < EPB_A / 256; ++k) {
        int e = base + k * 256 + t;
        if (e < ETOT) {
            int s, d; edge_sd(ei, e, s, d); (void)s;
            atomicAdd(&lb[d >> 6], 1);
        }
    }
    __syncthreads();
    for (int i = t; i < NBUCK; i += 256) {
        int c = lb[i];
        lb[i] = c ? atomicAdd(&bucket_cur[i], c) : 0;
    }
    __syncthreads();
    #pragma unroll 4
    for (int k = 0; k < EPB_A / 256; ++k) {
        int e = base + k * 256 + t;
        if (e < ETOT) {
            int s, d; edge_sd(ei, e, s, d);
            int pos = atomicAdd(&lb[d >> 6], 1);
            ebkt[pos] = ((unsigned)d << 16) | (unsigned)s;
        }
    }
}

// kB: per-bucket count + in-LDS scan + row_ptr write + within-bucket scatter
__global__ __launch_bounds__(256) void kB(const int* __restrict__ bucket_off,
                                          const unsigned* __restrict__ ebkt,
                                          int* __restrict__ row_ptr,
                                          int* __restrict__ src_sorted) {
    __shared__ int lc[64];
    int b = blockIdx.x, t = threadIdx.x;
    if (t < 64) lc[t] = 0;
    __syncthreads();
    int s0 = bucket_off[b], s1 = bucket_off[b + 1];
    for (int i = s0 + t; i < s1; i += 256) atomicAdd(&lc[(ebkt[i] >> 16) & 63], 1);
    __syncthreads();
    if (t < 64) {
        int v = lc[t];
        int inc = v;
        #pragma unroll
        for (int off = 1; off < 64; off <<= 1) {
            int u = __shfl_up(inc, off);
            if (t >= off) inc += u;
        }
        int ex = s0 + inc - v;
        row_ptr[b * 64 + t] = ex;
        lc[t] = ex;
    }
    __syncthreads();
    for (int i = s0 + t; i < s1; i += 256) {
        unsigned k = ebkt[i];
        int pos = atomicAdd(&lc[(k >> 16) & 63], 1);
        src_sorted[pos] = (int)(k & 0xffffu);
    }
}

// ---------------- GEMM + attention coefficients (layers 0/1: 128 -> 8x16) ----------------
// 256 threads; 64 nodes x 128 cols per block; each thread 8 nodes x 4 cols.
#define FMA4(xc, wv, i) \
    acc[i][0] = fmaf(xc, wv.x, acc[i][0]); \
    acc[i][1] = fmaf(xc, wv.y, acc[i][1]); \
    acc[i][2] = fmaf(xc, wv.z, acc[i][2]); \
    acc[i][3] = fmaf(xc, wv.w, acc[i][3]);

__global__ __launch_bounds__(256) void gemm_att128(
    const float* __restrict__ x, const float* __restrict__ W,
    const float* __restrict__ asrc, const float* __restrict__ adst,
    unsigned* __restrict__ hb, float* __restrict__ als, float* __restrict__ ald)
{
    __shared__ float ws[32 * 128];   // [32k][128c] 16KB
    __shared__ float xs[64 * 32];    // [64n][32k]  8KB
    int t = threadIdx.x;
    int tx = t & 31, ty = t >> 5;    // cols 4tx..4tx+3 ; nodes ty*8..ty*8+7
    int n0 = blockIdx.x * 64;

    float acc[8][4];
    #pragma unroll
    for (int i = 0; i < 8; ++i)
        #pragma unroll
        for (int j = 0; j < 4; ++j) acc[i][j] = 0.f;

    for (int kt = 0; kt < 4; ++kt) {
        const float4* Wg = (const float4*)(W + (size_t)kt * 32 * 128);
        #pragma unroll
        for (int i = 0; i < 4; ++i) ((float4*)ws)[i * 256 + t] = Wg[i * 256 + t];
        #pragma unroll
        for (int q = 0; q < 2; ++q) {
            int idx = q * 256 + t;
            int n = idx >> 3, f4 = idx & 7;
            int ng = n0 + n; if (ng >= NN) ng = NN - 1;
            ((float4*)xs)[idx] = ((const float4*)(x + (size_t)ng * 128))[kt * 8 + f4];
        }
        __syncthreads();
        #pragma unroll
        for (int kc = 0; kc < 8; ++kc) {
            float4 wv0 = ((const float4*)(ws + (kc * 4 + 0) * 128))[tx];
            float4 wv1 = ((const float4*)(ws + (kc * 4 + 1) * 128))[tx];
            float4 wv2 = ((const float4*)(ws + (kc * 4 + 2) * 128))[tx];
            float4 wv3 = ((const float4*)(ws + (kc * 4 + 3) * 128))[tx];
            #pragma unroll
            for (int i = 0; i < 8; ++i) {
                float4 xv = ((const float4*)(xs + (ty * 8 + i) * 32))[kc];
                FMA4(xv.x, wv0, i)
                FMA4(xv.y, wv1, i)
                FMA4(xv.z, wv2, i)
                FMA4(xv.w, wv3, i)
            }
        }
        __syncthreads();
    }

    float4 as4 = ((const float4*)asrc)[tx];
    float4 ad4 = ((const float4*)adst)[tx];
    int hd = tx >> 2;
    #pragma unroll
    for (int i = 0; i < 8; ++i) {
        int n = n0 + ty * 8 + i;
        if (n < NN) {
            uint2 hp;
            hp.x = pack_bf16x2(acc[i][0], acc[i][1]);
            hp.y = pack_bf16x2(acc[i][2], acc[i][3]);
            ((uint2*)(hb + (size_t)n * 64))[tx] = hp;
            float v1 = acc[i][0] * as4.x + acc[i][1] * as4.y + acc[i][2] * as4.z + acc[i][3] * as4.w;
            float v2 = acc[i][0] * ad4.x + acc[i][1] * ad4.y + acc[i][2] * ad4.z + acc[i][3] * ad4.w;
            v1 += __shfl_xor(v1, 1); v1 += __shfl_xor(v1, 2);
            v2 += __shfl_xor(v2, 1); v2 += __shfl_xor(v2, 2);
            if ((tx & 3) == 0) { als[n * 8 + hd] = v1; ald[n * 8 + hd] = v2; }
        }
    }
}

// ---------------- GEMM + attention (layer 2: 128 -> 1x40, bf16-packed output) ----------------
__global__ __launch_bounds__(256) void gemm_att40(
    const float* __restrict__ x, const float* __restrict__ W,
    const float* __restrict__ asrc, const float* __restrict__ adst,
    unsigned* __restrict__ hb40, float* __restrict__ als, float* __restrict__ ald)
{
    __shared__ float ws[128 * 40];
    __shared__ float xs[16 * 128];
    int t = threadIdx.x;
    int n0 = blockIdx.x * 16;
    #pragma unroll
    for (int i = 0; i < 5; ++i) ((float4*)ws)[i * 256 + t] = ((const float4*)W)[i * 256 + t];
    #pragma unroll
    for (int q = 0; q < 2; ++q) {
        int idx = q * 256 + t;
        int n = idx >> 5, kc = idx & 31;
        ((float4*)xs)[idx] = ((const float4*)(x + (size_t)(n0 + n) * 128))[kc];
    }
    __syncthreads();
    int w = t >> 6, c = t & 63;
    int cc = c < 40 ? c : 39;
    float acc[4] = {0.f, 0.f, 0.f, 0.f};
    #pragma unroll 4
    for (int kc = 0; kc < 32; ++kc) {
        float w0 = ws[(kc * 4 + 0) * 40 + cc];
        float w1 = ws[(kc * 4 + 1) * 40 + cc];
        float w2 = ws[(kc * 4 + 2) * 40 + cc];
        float w3 = ws[(kc * 4 + 3) * 40 + cc];
        #pragma unroll
        for (int i = 0; i < 4; ++i) {
            float4 xv = ((const float4*)(xs + (4 * w + i) * 128))[kc];
            acc[i] = fmaf(xv.x, w0, acc[i]);
            acc[i] = fmaf(xv.y, w1, acc[i]);
            acc[i] = fmaf(xv.z, w2, acc[i]);
            acc[i] = fmaf(xv.w, w3, acc[i]);
        }
    }
    float a_s = (c < 40) ? asrc[c] : 0.f;
    float a_d = (c < 40) ? adst[c] : 0.f;
    #pragma unroll
    for (int i = 0; i < 4; ++i) {
        int n = n0 + 4 * w + i;
        float nb = __shfl_xor(acc[i], 1);
        if ((c & 1) == 0 && c < 40) hb40[(size_t)n * 32 + (c >> 1)] = pack_bf16x2(acc[i], nb);
        float v1 = acc[i] * a_s, v2 = acc[i] * a_d;
        #pragma unroll
        for (int m = 1; m < 64; m <<= 1) { v1 += __shfl_xor(v1, m); v2 += __shfl_xor(v2, m); }
        if (c == 0) { als[n] = v1; ald[n] = v2; }
    }
}

// ---------------- fused single-pass softmax + aggregate + finalize ----------------
// TWO nodes per wave: lanes 0-31 -> node 2wp, lanes 32-63 -> node 2wp+1.
// Lane l (0-31) covers features 4l..4l+3 (one uint2), head = l>>2.
template<bool RELU>
__global__ void dst_agg128(const int* __restrict__ row_ptr, const int* __restrict__ src_sorted,
                           const float* __restrict__ als, const float* __restrict__ ald,
                           const unsigned* __restrict__ hb, const float* __restrict__ bias,
                           float* __restrict__ out)
{
    int wp = (blockIdx.x * blockDim.x + threadIdx.x) >> 6;
    if (wp >= NN / 2) return;
    int lane = threadIdx.x & 63;
    int half = lane >> 5, l = lane & 31;
    int node = 2 * wp + half;
    int myh = l >> 2;
    float aldv = ald[node * 8 + myh];
    int i = row_ptr[node], end = row_ptr[node + 1];
    float4 acc = make_float4(0.f, 0.f, 0.f, 0.f);
    float den = 0.f;
    while (__any(i + 4 <= end)) {
        if (i + 4 <= end) {
            int s0 = src_sorted[i], s1 = src_sorted[i + 1], s2 = src_sorted[i + 2], s3 = src_sorted[i + 3];
            float e0 = als[s0 * 8 + myh] + aldv;
            float e1 = als[s1 * 8 + myh] + aldv;
            float e2 = als[s2 * 8 + myh] + aldv;
            float e3 = als[s3 * 8 + myh] + aldv;
            uint2 p0 = ((const uint2*)(hb + (size_t)s0 * 64))[l];
            uint2 p1 = ((const uint2*)(hb + (size_t)s1 * 64))[l];
            uint2 p2 = ((const uint2*)(hb + (size_t)s2 * 64))[l];
            uint2 p3 = ((const uint2*)(hb + (size_t)s3 * 64))[l];
            e0 = e0 > 0.f ? e0 : 0.2f * e0;
            e1 = e1 > 0.f ? e1 : 0.2f * e1;
            e2 = e2 > 0.f ? e2 : 0.2f * e2;
            e3 = e3 > 0.f ? e3 : 0.2f * e3;
            float a0 = __expf(e0), a1 = __expf(e1), a2 = __expf(e2), a3 = __expf(e3);
            den += (a0 + a1) + (a2 + a3);
            float2 u0 = unpack_bf16x2(p0.x), v0 = unpack_bf16x2(p0.y);
            float2 u1 = unpack_bf16x2(p1.x), v1 = unpack_bf16x2(p1.y);
            float2 u2 = unpack_bf16x2(p2.x), v2 = unpack_bf16x2(p2.y);
            float2 u3 = unpack_bf16x2(p3.x), v3 = unpack_bf16x2(p3.y);
            acc.x = fmaf(u0.x, a0, acc.x); acc.y = fmaf(u0.y, a0, acc.y);
            acc.z = fmaf(v0.x, a0, acc.z); acc.w = fmaf(v0.y, a0, acc.w);
            acc.x = fmaf(u1.x, a1, acc.x); acc.y = fmaf(u1.y, a1, acc.y);
            acc.z = fmaf(v1.x, a1, acc.z); acc.w = fmaf(v1.y, a1, acc.w);
            acc.x = fmaf(u2.x, a2, acc.x); acc.y = fmaf(u2.y, a2, acc.y);
            acc.z = fmaf(v2.x, a2, acc.z); acc.w = fmaf(v2.y, a2, acc.w);
            acc.x = fmaf(u3.x, a3, acc.x); acc.y = fmaf(u3.y, a3, acc.y);
            acc.z = fmaf(v3.x, a3, acc.z); acc.w = fmaf(v3.y, a3, acc.w);
            i += 4;
        }
    }
    while (__any(i < end)) {
        if (i < end) {
            int s0 = src_sorted[i];
            float e0 = als[s0 * 8 + myh] + aldv;
            e0 = e0 > 0.f ? e0 : 0.2f * e0;
            float a0 = __expf(e0);
            den += a0;
            uint2 p0 = ((const uint2*)(hb + (size_t)s0 * 64))[l];
            float2 u0 = unpack_bf16x2(p0.x), v0 = unpack_bf16x2(p0.y);
            acc.x = fmaf(u0.x, a0, acc.x); acc.y = fmaf(u0.y, a0, acc.y);
            acc.z = fmaf(v0.x, a0, acc.z); acc.w = fmaf(v0.y, a0, acc.w);
            ++i;
        }
    }
    float inv = 1.f / (den + 1e-16f);
    float4 bv = ((const float4*)bias)[l];
    float4 o;
    o.x = acc.x * inv + bv.x;
    o.y = acc.y * inv + bv.y;
    o.z = acc.z * inv + bv.z;
    o.w = acc.w * inv + bv.w;
    if (RELU) {
        o.x = fmaxf(o.x, 0.f); o.y = fmaxf(o.y, 0.f);
        o.z = fmaxf(o.z, 0.f); o.w = fmaxf(o.w, 0.f);
    }
    ((float4*)(out + (size_t)node * 128))[l] = o;
}

// H=1, C=40: FOUR nodes per wave (16 lanes each; lanes l<10 own uint2 feature pairs).
// Loads unpredicated: pad uints (0xAA poison) decode to finite bf16; results unused.
__global__ void dst_agg40(const int* __restrict__ row_ptr, const int* __restrict__ src_sorted,
                          const float* __restrict__ als, const float* __restrict__ ald,
                          const unsigned* __restrict__ hb40, const float* __restrict__ bias,
                          float* __restrict__ out)
{
    int wp = (blockIdx.x * blockDim.x + threadIdx.x) >> 6;
    if (wp >= NN / 4) return;
    int lane = threadIdx.x & 63;
    int q = lane >> 4, l = lane & 15;
    int node = 4 * wp + q;
    float aldv = ald[node];
    int i = row_ptr[node], end = row_ptr[node + 1];
    float4 acc = make_float4(0.f, 0.f, 0.f, 0.f);
    float den = 0.f;
    while (__any(i + 4 <= end)) {
        if (i + 4 <= end) {
            int s0 = src_sorted[i], s1 = src_sorted[i + 1], s2 = src_sorted[i + 2], s3 = src_sorted[i + 3];
            float e0 = als[s0] + aldv;
            float e1 = als[s1] + aldv;
            float e2 = als[s2] + aldv;
            float e3 = als[s3] + aldv;
            uint2 p0 = ((const uint2*)(hb40 + (size_t)s0 * 32))[l];
            uint2 p1 = ((const uint2*)(hb40 + (size_t)s1 * 32))[l];
            uint2 p2 = ((const uint2*)(hb40 + (size_t)s2 * 32))[l];
            uint2 p3 = ((const uint2*)(hb40 + (size_t)s3 * 32))[l];
            e0 = e0 > 0.f ? e0 : 0.2f * e0;
            e1 = e1 > 0.f ? e1 : 0.2f * e1;
            e2 = e2 > 0.f ? e2 : 0.2f * e2;
            e3 = e3 > 0.f ? e3 : 0.2f * e3;
            float a0 = __expf(e0), a1 = __expf(e1), a2 = __expf(e2), a3 = __expf(e3);
            den += (a0 + a1) + (a2 + a3);
            float2 u0 = unpack_bf16x2(p0.x), v0 = unpack_bf16x2(p0.y);
            float2 u1 = unpack_bf16x2(p1.x), v1 = unpack_bf16x2(p1.y);
            float2 u2 = unpack_bf16x2(p2.x), v2 = unpack_bf16x2(p2.y);
            float2 u3 = unpack_bf16x2(p3.x), v3 = unpack_bf16x2(p3.y);
            acc.x = fmaf(u0.x, a0, acc.x); acc.y = fmaf(u0.y, a0, acc.y);
            acc.z = fmaf(v0.x, a0, acc.z); acc.w = fmaf(v0.y, a0, acc.w);
            acc.x = fmaf(u1.x, a1, acc.x); acc.y = fmaf(u1.y, a1, acc.y);
            acc.z = fmaf(v1.x, a1, acc.z); acc.w = fmaf(v1.y, a1, acc.w);
            acc.x = fmaf(u2.x, a2, acc.x); acc.y = fmaf(u2.y, a2, acc.y);
            acc.z = fmaf(v2.x, a2, acc.z); acc.w = fmaf(v2.y, a2, acc.w);
            acc.x = fmaf(u3.x, a3, acc.x); acc.y = fmaf(u3.y, a3, acc.y);
            acc.z = fmaf(v3.x, a3, acc.z); acc.w = fmaf(v3.y, a3, acc.w);
            i += 4;
        }
    }
    while (__any(i < end)) {
        if (i < end) {
            int s0 = src_sorted[i];
            float e0 = als[s0] + aldv;
            e0 = e0 > 0.f ? e0 : 0.2f * e0;
            float a0 = __expf(e0);
            den += a0;
            uint2 p0 = ((const uint2*)(hb40 + (size_t)s0 * 32))[l];
            float2 u0 = unpack_bf16x2(p0.x), v0 = unpack_bf16x2(p0.y);
            acc.x = fmaf(u0.x, a0, acc.x); acc.y = fmaf(u0.y, a0, acc.y);
            acc.z = fmaf(v0.x, a0, acc.z); acc.w = fmaf(v0.y, a0, acc.w);
            ++i;
        }
    }
    if (l < 10) {
        float inv = 1.f / (den + 1e-16f);
        float4 bv = ((const float4*)bias)[l];
        float4 o;
        o.x = acc.x * inv + bv.x;
        o.y = acc.y * inv + bv.y;
        o.z = acc.z * inv + bv.z;
        o.w = acc.w * inv + bv.w;
        ((float4*)(out + (size_t)node * 40))[l] = o;
    }
}

extern "C" void kernel_launch(void* const* d_in, const int* in_sizes, int n_in,
                              void* d_out, int out_size, void* d_ws, size_t ws_size,
                              hipStream_t stream) {
    const float* x   = (const float*)d_in[0];
    const int*   ei  = (const int*)d_in[1];
    const float* W0  = (const float*)d_in[2];
    const float* as0 = (const float*)d_in[3];
    const float* ad0 = (const float*)d_in[4];
    const float* b0  = (const float*)d_in[5];
    const float* W1  = (const float*)d_in[6];
    const float* as1 = (const float*)d_in[7];
    const float* ad1 = (const float*)d_in[8];
    const float* b1  = (const float*)d_in[9];
    const float* W2  = (const float*)d_in[10];
    const float* as2 = (const float*)d_in[11];
    const float* ad2 = (const float*)d_in[12];
    const float* b2  = (const float*)d_in[13];
    float* out = (float*)d_out;

    float* ws = (float*)d_ws;
    size_t off = 0;
    unsigned* hb   = (unsigned*)(ws + off); off += (size_t)NN * 64;  // bf16 h, layers 0/1
    float* fA      = ws + off; off += (size_t)NN * 128;
    float* fB      = ws + off; off += (size_t)NN * 128;
    unsigned* hb40 = (unsigned*)(ws + off); off += (size_t)NN * 32;  // bf16 h, layer 2
    float* als     = ws + off; off += (size_t)NN * 8;
    float* ald     = ws + off; off += (size_t)NN * 8;
    int* ibase       = (int*)(ws + off);
    int* bucket_cnt  = ibase; ibase += NBUCK;
    int* bucket_off  = ibase; ibase += NBUCK + 2;
    int* bucket_cur  = ibase; ibase += NBUCK;
    int* row_ptr     = ibase; ibase += NCNT + 1;
    unsigned* ebkt   = (unsigned*)ibase; ibase += ETOT;
    int* src_sorted  = ibase; ibase += ETOT;

    const int TB = 256;

    // ---- CSR build (bucketed counting sort; shared by all 3 layers) ----
    hipMemsetAsync(bucket_cnt, 0, NBUCK * sizeof(int), stream);
    kA1<<<NBLK_A, 256, 0, stream>>>(ei, bucket_cnt);
    kA2<<<1, 1024, 0, stream>>>(bucket_cnt, bucket_off, bucket_cur);
    kA3<<<NBLK_A, 256, 0, stream>>>(ei, bucket_cur, ebkt);
    kB<<<NBUCK, 256, 0, stream>>>(bucket_off, ebkt, row_ptr, src_sorted);

    const int GG128 = (NN + 63) / 64;                 // 782
    const int GG40  = NN / 16;                        // 3125 (exact)
    const int GAGG  = ((NN / 2) * 64 + TB - 1) / TB;  // 2 nodes per wave -> 6250
    const int GAGG4 = ((NN / 4) * 64 + TB - 1) / TB;  // 4 nodes per wave -> 3125

    // ---- Layer 0 ----
    gemm_att128<<<GG128, 256, 0, stream>>>(x, W0, as0, ad0, hb, als, ald);
    dst_agg128<true><<<GAGG, TB, 0, stream>>>(row_ptr, src_sorted, als, ald, hb, b0, fA);

    // ---- Layer 1 ----
    gemm_att128<<<GG128, 256, 0, stream>>>(fA, W1, as1, ad1, hb, als, ald);
    dst_agg128<true><<<GAGG, TB, 0, stream>>>(row_ptr, src_sorted, als, ald, hb, b1, fB);

    // ---- Layer 2 ----
    gemm_att40<<<GG40, 256, 0, stream>>>(fB, W2, as2, ad2, hb40, als, ald);
    dst_agg40<<<GAGG4, TB, 0, stream>>>(row_ptr, src_sorted, als, ald, hb40, b2, out);
}

// Round 10
// 244.297 us; speedup vs baseline: 1.3014x; 1.0120x over previous
//
#include <hip/hip_runtime.h>

#define NN    50000
#define ERAW  800000
#define ETOT  850000
#define NBUCK 782            // ceil(NN/64) buckets of 64 dst nodes
#define EPB_A 4096           // edges per block in bucketing passes
#define NBLK_A ((ETOT + EPB_A - 1) / EPB_A)   // 208
#define NCNT  (NBUCK * 64)   // 50048 (padded per-dst count array)

__device__ __forceinline__ void edge_sd(const int* __restrict__ ei, int e, int& s, int& d) {
    if (e < ERAW) { s = ei[e]; d = ei[ERAW + e]; }
    else { int n = e - ERAW; s = n; d = n; }
}

// bf16 pack/unpack (RNE), 2 elements per uint: low16 = a, high16 = b
__device__ __forceinline__ unsigned pack_bf16x2(float a, float b) {
    unsigned ua = __float_as_uint(a), ub = __float_as_uint(b);
    ua += 0x7fffu + ((ua >> 16) & 1u);
    ub += 0x7fffu + ((ub >> 16) & 1u);
    return (ua >> 16) | (ub & 0xffff0000u);
}
__device__ __forceinline__ float2 unpack_bf16x2(unsigned v) {
    float2 r;
    r.x = __uint_as_float(v << 16);
    r.y = __uint_as_float(v & 0xffff0000u);
    return r;
}

// ---------------- CSR build: two-level bucketed counting sort ----------------
__global__ __launch_bounds__(256) void kA1(const int* __restrict__ ei, int* __restrict__ bucket_cnt) {
    __shared__ int lb[NBUCK];
    int t = threadIdx.x;
    for (int i = t; i < NBUCK; i += 256) lb[i] = 0;
    __syncthreads();
    int base = blockIdx.x * EPB_A;
    #pragma unroll 4
    for (int k = 0; k < EPB_A / 256; ++k) {
        int e = base + k * 256 + t;
        if (e < ETOT) {
            int s, d; edge_sd(ei, e, s, d); (void)s;
            atomicAdd(&lb[d >> 6], 1);
        }
    }
    __syncthreads();
    for (int i = t; i < NBUCK; i += 256) if (lb[i]) atomicAdd(&bucket_cnt[i], lb[i]);
}

__global__ void kA2(const int* __restrict__ bucket_cnt, int* __restrict__ bucket_off,
                    int* __restrict__ bucket_cur) {
    __shared__ int tmp[1024];
    int t = threadIdx.x;
    int v = (t < NBUCK) ? bucket_cnt[t] : 0;
    tmp[t] = v;
    __syncthreads();
    for (int off = 1; off < 1024; off <<= 1) {
        int u = (t >= off) ? tmp[t - off] : 0;
        __syncthreads();
        tmp[t] += u;
        __syncthreads();
    }
    if (t < NBUCK) { int ex = tmp[t] - v; bucket_off[t] = ex; bucket_cur[t] = ex; }
    if (t == 0) bucket_off[NBUCK] = ETOT;
}

__global__ __launch_bounds__(256) void kA3(const int* __restrict__ ei, int* __restrict__ bucket_cur,
                                           unsigned* __restrict__ ebkt) {
    __shared__ int lb[NBUCK];
    int t = threadIdx.x;
    for (int i = t; i < NBUCK; i += 256) lb[i] = 0;
    __syncthreads();
    int base = blockIdx.x * EPB_A;
    #pragma unroll 4
    for (int k = 0; k < EPB_A / 256; ++k) {
        int e = base + k * 256 + t;
        if (e < ETOT) {
            int s, d; edge_sd(ei, e, s, d); (void)s;
            atomicAdd(&lb[d >> 6], 1);
        }
    }
    __syncthreads();
    for (int i = t; i < NBUCK; i += 256) {
        int c = lb[i];
        lb[i] = c ? atomicAdd(&bucket_cur[i], c) : 0;
    }
    __syncthreads();
    #pragma unroll 4
    for (int k = 0; k < EPB_A / 256; ++k) {
        int e = base + k * 256 + t;
        if (e < ETOT) {
            int s, d; edge_sd(ei, e, s, d);
            int pos = atomicAdd(&lb[d >> 6], 1);
            ebkt[pos] = ((unsigned)d << 16) | (unsigned)s;
        }
    }
}

// kB: per-bucket count + in-LDS scan + row_ptr write + within-bucket scatter
__global__ __launch_bounds__(256) void kB(const int* __restrict__ bucket_off,
                                          const unsigned* __restrict__ ebkt,
                                          int* __restrict__ row_ptr,
                                          int* __restrict__ src_sorted) {
    __shared__ int lc[64];
    int b = blockIdx.x, t = threadIdx.x;
    if (t < 64) lc[t] = 0;
    __syncthreads();
    int s0 = bucket_off[b], s1 = bucket_off[b + 1];
    for (int i = s0 + t; i < s1; i += 256) atomicAdd(&lc[(ebkt[i] >> 16) & 63], 1);
    __syncthreads();
    if (t < 64) {
        int v = lc[t];
        int inc = v;
        #pragma unroll
        for (int off = 1; off < 64; off <<= 1) {
            int u = __shfl_up(inc, off);
            if (t >= off) inc += u;
        }
        int ex = s0 + inc - v;
        row_ptr[b * 64 + t] = ex;
        lc[t] = ex;
    }
    __syncthreads();
    for (int i = s0 + t; i < s1; i += 256) {
        unsigned k = ebkt[i];
        int pos = atomicAdd(&lc[(k >> 16) & 63], 1);
        src_sorted[pos] = (int)(k & 0xffffu);
    }
}

// ---------------- GEMM + attention coefficients (layers 0/1: 128 -> 8x16) ----------------
// 256 threads; 64 nodes x 128 cols per block; each thread 8 nodes x 4 cols.
#define FMA4(xc, wv, i) \
    acc[i][0] = fmaf(xc, wv.x, acc[i][0]); \
    acc[i][1] = fmaf(xc, wv.y, acc[i][1]); \
    acc[i][2] = fmaf(xc, wv.z, acc[i][2]); \
    acc[i][3] = fmaf(xc, wv.w, acc[i][3]);

__global__ __launch_bounds__(256) void gemm_att128(
    const float* __restrict__ x, const float* __restrict__ W,
    const float* __restrict__ asrc, const float* __restrict__ adst,
    unsigned* __restrict__ hb, float* __restrict__ als, float* __restrict__ ald)
{
    __shared__ float ws[32 * 128];   // [32k][128c] 16KB
    __shared__ float xs[64 * 32];    // [64n][32k]  8KB
    int t = threadIdx.x;
    int tx = t & 31, ty = t >> 5;    // cols 4tx..4tx+3 ; nodes ty*8..ty*8+7
    int n0 = blockIdx.x * 64;

    float acc[8][4];
    #pragma unroll
    for (int i = 0; i < 8; ++i)
        #pragma unroll
        for (int j = 0; j < 4; ++j) acc[i][j] = 0.f;

    for (int kt = 0; kt < 4; ++kt) {
        const float4* Wg = (const float4*)(W + (size_t)kt * 32 * 128);
        #pragma unroll
        for (int i = 0; i < 4; ++i) ((float4*)ws)[i * 256 + t] = Wg[i * 256 + t];
        #pragma unroll
        for (int q = 0; q < 2; ++q) {
            int idx = q * 256 + t;
            int n = idx >> 3, f4 = idx & 7;
            int ng = n0 + n; if (ng >= NN) ng = NN - 1;
            ((float4*)xs)[idx] = ((const float4*)(x + (size_t)ng * 128))[kt * 8 + f4];
        }
        __syncthreads();
        #pragma unroll
        for (int kc = 0; kc < 8; ++kc) {
            float4 wv0 = ((const float4*)(ws + (kc * 4 + 0) * 128))[tx];
            float4 wv1 = ((const float4*)(ws + (kc * 4 + 1) * 128))[tx];
            float4 wv2 = ((const float4*)(ws + (kc * 4 + 2) * 128))[tx];
            float4 wv3 = ((const float4*)(ws + (kc * 4 + 3) * 128))[tx];
            #pragma unroll
            for (int i = 0; i < 8; ++i) {
                float4 xv = ((const float4*)(xs + (ty * 8 + i) * 32))[kc];
                FMA4(xv.x, wv0, i)
                FMA4(xv.y, wv1, i)
                FMA4(xv.z, wv2, i)
                FMA4(xv.w, wv3, i)
            }
        }
        __syncthreads();
    }

    float4 as4 = ((const float4*)asrc)[tx];
    float4 ad4 = ((const float4*)adst)[tx];
    int hd = tx >> 2;
    #pragma unroll
    for (int i = 0; i < 8; ++i) {
        int n = n0 + ty * 8 + i;
        if (n < NN) {
            uint2 hp;
            hp.x = pack_bf16x2(acc[i][0], acc[i][1]);
            hp.y = pack_bf16x2(acc[i][2], acc[i][3]);
            ((uint2*)(hb + (size_t)n * 64))[tx] = hp;
            float v1 = acc[i][0] * as4.x + acc[i][1] * as4.y + acc[i][2] * as4.z + acc[i][3] * as4.w;
            float v2 = acc[i][0] * ad4.x + acc[i][1] * ad4.y + acc[i][2] * ad4.z + acc[i][3] * ad4.w;
            v1 += __shfl_xor(v1, 1); v1 += __shfl_xor(v1, 2);
            v2 += __shfl_xor(v2, 1); v2 += __shfl_xor(v2, 2);
            if ((tx & 3) == 0) { als[n * 8 + hd] = v1; ald[n * 8 + hd] = v2; }
        }
    }
}

// ---------------- GEMM + attention (layer 2: 128 -> 1x40, bf16-packed output) ----------------
__global__ __launch_bounds__(256) void gemm_att40(
    const float* __restrict__ x, const float* __restrict__ W,
    const float* __restrict__ asrc, const float* __restrict__ adst,
    unsigned* __restrict__ hb40, float* __restrict__ als, float* __restrict__ ald)
{
    __shared__ float ws[128 * 40];
    __shared__ float xs[16 * 128];
    int t = threadIdx.x;
    int n0 = blockIdx.x * 16;
    #pragma unroll
    for (int i = 0; i < 5; ++i) ((float4*)ws)[i * 256 + t] = ((const float4*)W)[i * 256 + t];
    #pragma unroll
    for (int q = 0; q < 2; ++q) {
        int idx = q * 256 + t;
        int n = idx >> 5, kc = idx & 31;
        ((float4*)xs)[idx] = ((const float4*)(x + (size_t)(n0 + n) * 128))[kc];
    }
    __syncthreads();
    int w = t >> 6, c = t & 63;
    int cc = c < 40 ? c : 39;
    float acc[4] = {0.f, 0.f, 0.f, 0.f};
    #pragma unroll 4
    for (int kc = 0; kc < 32; ++kc) {
        float w0 = ws[(kc * 4 + 0) * 40 + cc];
        float w1 = ws[(kc * 4 + 1) * 40 + cc];
        float w2 = ws[(kc * 4 + 2) * 40 + cc];
        float w3 = ws[(kc * 4 + 3) * 40 + cc];
        #pragma unroll
        for (int i = 0; i < 4; ++i) {
            float4 xv = ((const float4*)(xs + (4 * w + i) * 128))[kc];
            acc[i] = fmaf(xv.x, w0, acc[i]);
            acc[i] = fmaf(xv.y, w1, acc[i]);
            acc[i] = fmaf(xv.z, w2, acc[i]);
            acc[i] = fmaf(xv.w, w3, acc[i]);
        }
    }
    float a_s = (c < 40) ? asrc[c] : 0.f;
    float a_d = (c < 40) ? adst[c] : 0.f;
    #pragma unroll
    for (int i = 0; i < 4; ++i) {
        int n = n0 + 4 * w + i;
        float nb = __shfl_xor(acc[i], 1);
        if ((c & 1) == 0 && c < 40) hb40[(size_t)n * 32 + (c >> 1)] = pack_bf16x2(acc[i], nb);
        float v1 = acc[i] * a_s, v2 = acc[i] * a_d;
        #pragma unroll
        for (int m = 1; m < 64; m <<= 1) { v1 += __shfl_xor(v1, m); v2 += __shfl_xor(v2, m); }
        if (c == 0) { als[n] = v1; ald[n] = v2; }
    }
}

// ---------------- fused single-pass softmax + aggregate + finalize ----------------
// FOUR nodes per wave: 16 lanes/node; lane l covers features 8l..8l+7 (one uint4),
// head = l>>1. One wave-step retires 4 edges.
template<bool RELU>
__global__ void dst_agg128(const int* __restrict__ row_ptr, const int* __restrict__ src_sorted,
                           const float* __restrict__ als, const float* __restrict__ ald,
                           const unsigned* __restrict__ hb, const float* __restrict__ bias,
                           float* __restrict__ out)
{
    int wp = (blockIdx.x * blockDim.x + threadIdx.x) >> 6;
    if (wp >= NN / 4) return;
    int lane = threadIdx.x & 63;
    int q = lane >> 4, l = lane & 15;
    int node = 4 * wp + q;
    int myh = l >> 1;
    float aldv = ald[node * 8 + myh];
    int i = row_ptr[node], end = row_ptr[node + 1];
    float4 accA = make_float4(0.f, 0.f, 0.f, 0.f);
    float4 accB = make_float4(0.f, 0.f, 0.f, 0.f);
    float den = 0.f;
    while (__any(i + 4 <= end)) {
        if (i + 4 <= end) {
            int s0 = src_sorted[i], s1 = src_sorted[i + 1], s2 = src_sorted[i + 2], s3 = src_sorted[i + 3];
            float e0 = als[s0 * 8 + myh] + aldv;
            float e1 = als[s1 * 8 + myh] + aldv;
            float e2 = als[s2 * 8 + myh] + aldv;
            float e3 = als[s3 * 8 + myh] + aldv;
            uint4 p0 = ((const uint4*)(hb + (size_t)s0 * 64))[l];
            uint4 p1 = ((const uint4*)(hb + (size_t)s1 * 64))[l];
            uint4 p2 = ((const uint4*)(hb + (size_t)s2 * 64))[l];
            uint4 p3 = ((const uint4*)(hb + (size_t)s3 * 64))[l];
            e0 = e0 > 0.f ? e0 : 0.2f * e0;
            e1 = e1 > 0.f ? e1 : 0.2f * e1;
            e2 = e2 > 0.f ? e2 : 0.2f * e2;
            e3 = e3 > 0.f ? e3 : 0.2f * e3;
            float a0 = __expf(e0), a1 = __expf(e1), a2 = __expf(e2), a3 = __expf(e3);
            den += (a0 + a1) + (a2 + a3);
            float2 t0, t1;
            t0 = unpack_bf16x2(p0.x); t1 = unpack_bf16x2(p0.y);
            accA.x = fmaf(t0.x, a0, accA.x); accA.y = fmaf(t0.y, a0, accA.y);
            accA.z = fmaf(t1.x, a0, accA.z); accA.w = fmaf(t1.y, a0, accA.w);
            t0 = unpack_bf16x2(p0.z); t1 = unpack_bf16x2(p0.w);
            accB.x = fmaf(t0.x, a0, accB.x); accB.y = fmaf(t0.y, a0, accB.y);
            accB.z = fmaf(t1.x, a0, accB.z); accB.w = fmaf(t1.y, a0, accB.w);
            t0 = unpack_bf16x2(p1.x); t1 = unpack_bf16x2(p1.y);
            accA.x = fmaf(t0.x, a1, accA.x); accA.y = fmaf(t0.y, a1, accA.y);
            accA.z = fmaf(t1.x, a1, accA.z); accA.w = fmaf(t1.y, a1, accA.w);
            t0 = unpack_bf16x2(p1.z); t1 = unpack_bf16x2(p1.w);
            accB.x = fmaf(t0.x, a1, accB.x); accB.y = fmaf(t0.y, a1, accB.y);
            accB.z = fmaf(t1.x, a1, accB.z); accB.w = fmaf(t1.y, a1, accB.w);
            t0 = unpack_bf16x2(p2.x); t1 = unpack_bf16x2(p2.y);
            accA.x = fmaf(t0.x, a2, accA.x); accA.y = fmaf(t0.y, a2, accA.y);
            accA.z = fmaf(t1.x, a2, accA.z); accA.w = fmaf(t1.y, a2, accA.w);
            t0 = unpack_bf16x2(p2.z); t1 = unpack_bf16x2(p2.w);
            accB.x = fmaf(t0.x, a2, accB.x); accB.y = fmaf(t0.y, a2, accB.y);
            accB.z = fmaf(t1.x, a2, accB.z); accB.w = fmaf(t1.y, a2, accB.w);
            t0 = unpack_bf16x2(p3.x); t1 = unpack_bf16x2(p3.y);
            accA.x = fmaf(t0.x, a3, accA.x); accA.y = fmaf(t0.y, a3, accA.y);
            accA.z = fmaf(t1.x, a3, accA.z); accA.w = fmaf(t1.y, a3, accA.w);
            t0 = unpack_bf16x2(p3.z); t1 = unpack_bf16x2(p3.w);
            accB.x = fmaf(t0.x, a3, accB.x); accB.y = fmaf(t0.y, a3, accB.y);
            accB.z = fmaf(t1.x, a3, accB.z); accB.w = fmaf(t1.y, a3, accB.w);
            i += 4;
        }
    }
    while (__any(i < end)) {
        if (i < end) {
            int s0 = src_sorted[i];
            float e0 = als[s0 * 8 + myh] + aldv;
            e0 = e0 > 0.f ? e0 : 0.2f * e0;
            float a0 = __expf(e0);
            den += a0;
            uint4 p0 = ((const uint4*)(hb + (size_t)s0 * 64))[l];
            float2 t0 = unpack_bf16x2(p0.x), t1 = unpack_bf16x2(p0.y);
            accA.x = fmaf(t0.x, a0, accA.x); accA.y = fmaf(t0.y, a0, accA.y);
            accA.z = fmaf(t1.x, a0, accA.z); accA.w = fmaf(t1.y, a0, accA.w);
            t0 = unpack_bf16x2(p0.z); t1 = unpack_bf16x2(p0.w);
            accB.x = fmaf(t0.x, a0, accB.x); accB.y = fmaf(t0.y, a0, accB.y);
            accB.z = fmaf(t1.x, a0, accB.z); accB.w = fmaf(t1.y, a0, accB.w);
            ++i;
        }
    }
    float inv = 1.f / (den + 1e-16f);
    float4 bvA = ((const float4*)bias)[2 * l];
    float4 bvB = ((const float4*)bias)[2 * l + 1];
    float4 oA, oB;
    oA.x = accA.x * inv + bvA.x; oA.y = accA.y * inv + bvA.y;
    oA.z = accA.z * inv + bvA.z; oA.w = accA.w * inv + bvA.w;
    oB.x = accB.x * inv + bvB.x; oB.y = accB.y * inv + bvB.y;
    oB.z = accB.z * inv + bvB.z; oB.w = accB.w * inv + bvB.w;
    if (RELU) {
        oA.x = fmaxf(oA.x, 0.f); oA.y = fmaxf(oA.y, 0.f);
        oA.z = fmaxf(oA.z, 0.f); oA.w = fmaxf(oA.w, 0.f);
        oB.x = fmaxf(oB.x, 0.f); oB.y = fmaxf(oB.y, 0.f);
        oB.z = fmaxf(oB.z, 0.f); oB.w = fmaxf(oB.w, 0.f);
    }
    ((float4*)(out + (size_t)node * 128))[2 * l]     = oA;
    ((float4*)(out + (size_t)node * 128))[2 * l + 1] = oB;
}

// H=1, C=40: FOUR nodes per wave (16 lanes each; lanes l<10 own uint2 feature pairs).
// Loads unpredicated: pad uints (0xAA poison) decode to finite bf16; results unused.
__global__ void dst_agg40(const int* __restrict__ row_ptr, const int* __restrict__ src_sorted,
                          const float* __restrict__ als, const float* __restrict__ ald,
                          const unsigned* __restrict__ hb40, const float* __restrict__ bias,
                          float* __restrict__ out)
{
    int wp = (blockIdx.x * blockDim.x + threadIdx.x) >> 6;
    if (wp >= NN / 4) return;
    int lane = threadIdx.x & 63;
    int q = lane >> 4, l = lane & 15;
    int node = 4 * wp + q;
    float aldv = ald[node];
    int i = row_ptr[node], end = row_ptr[node + 1];
    float4 acc = make_float4(0.f, 0.f, 0.f, 0.f);
    float den = 0.f;
    while (__any(i + 4 <= end)) {
        if (i + 4 <= end) {
            int s0 = src_sorted[i], s1 = src_sorted[i + 1], s2 = src_sorted[i + 2], s3 = src_sorted[i + 3];
            float e0 = als[s0] + aldv;
            float e1 = als[s1] + aldv;
            float e2 = als[s2] + aldv;
            float e3 = als[s3] + aldv;
            uint2 p0 = ((const uint2*)(hb40 + (size_t)s0 * 32))[l];
            uint2 p1 = ((const uint2*)(hb40 + (size_t)s1 * 32))[l];
            uint2 p2 = ((const uint2*)(hb40 + (size_t)s2 * 32))[l];
            uint2 p3 = ((const uint2*)(hb40 + (size_t)s3 * 32))[l];
            e0 = e0 > 0.f ? e0 : 0.2f * e0;
            e1 = e1 > 0.f ? e1 : 0.2f * e1;
            e2 = e2 > 0.f ? e2 : 0.2f * e2;
            e3 = e3 > 0.f ? e3 : 0.2f * e3;
            float a0 = __expf(e0), a1 = __expf(e1), a2 = __expf(e2), a3 = __expf(e3);
            den += (a0 + a1) + (a2 + a3);
            float2 u0 = unpack_bf16x2(p0.x), v0 = unpack_bf16x2(p0.y);
            float2 u1 = unpack_bf16x2(p1.x), v1 = unpack_bf16x2(p1.y);
            float2 u2 = unpack_bf16x2(p2.x), v2 = unpack_bf16x2(p2.y);
            float2 u3 = unpack_bf16x2(p3.x), v3 = unpack_bf16x2(p3.y);
            acc.x = fmaf(u0.x, a0, acc.x); acc.y = fmaf(u0.y, a0, acc.y);
            acc.z = fmaf(v0.x, a0, acc.z); acc.w = fmaf(v0.y, a0, acc.w);
            acc.x = fmaf(u1.x, a1, acc.x); acc.y = fmaf(u1.y, a1, acc.y);
            acc.z = fmaf(v1.x, a1, acc.z); acc.w = fmaf(v1.y, a1, acc.w);
            acc.x = fmaf(u2.x, a2, acc.x); acc.y = fmaf(u2.y, a2, acc.y);
            acc.z = fmaf(v2.x, a2, acc.z); acc.w = fmaf(v2.y, a2, acc.w);
            acc.x = fmaf(u3.x, a3, acc.x); acc.y = fmaf(u3.y, a3, acc.y);
            acc.z = fmaf(v3.x, a3, acc.z); acc.w = fmaf(v3.y, a3, acc.w);
            i += 4;
        }
    }
    while (__any(i < end)) {
        if (i < end) {
            int s0 = src_sorted[i];
            float e0 = als[s0] + aldv;
            e0 = e0 > 0.f ? e0 : 0.2f * e0;
            float a0 = __expf(e0);
            den += a0;
            uint2 p0 = ((const uint2*)(hb40 + (size_t)s0 * 32))[l];
            float2 u0 = unpack_bf16x2(p0.x), v0 = unpack_bf16x2(p0.y);
            acc.x = fmaf(u0.x, a0, acc.x); acc.y = fmaf(u0.y, a0, acc.y);
            acc.z = fmaf(v0.x, a0, acc.z); acc.w = fmaf(v0.y, a0, acc.w);
            ++i;
        }
    }
    if (l < 10) {
        float inv = 1.f / (den + 1e-16f);
        float4 bv = ((const float4*)bias)[l];
        float4 o;
        o.x = acc.x * inv + bv.x;
        o.y = acc.y * inv + bv.y;
        o.z = acc.z * inv + bv.z;
        o.w = acc.w * inv + bv.w;
        ((float4*)(out + (size_t)node * 40))[l] = o;
    }
}

extern "C" void kernel_launch(void* const* d_in, const int* in_sizes, int n_in,
                              void* d_out, int out_size, void* d_ws, size_t ws_size,
                              hipStream_t stream) {
    const float* x   = (const float*)d_in[0];
    const int*   ei  = (const int*)d_in[1];
    const float* W0  = (const float*)d_in[2];
    const float* as0 = (const float*)d_in[3];
    const float* ad0 = (const float*)d_in[4];
    const float* b0  = (const float*)d_in[5];
    const float* W1  = (const float*)d_in[6];
    const float* as1 = (const float*)d_in[7];
    const float* ad1 = (const float*)d_in[8];
    const float* b1  = (const float*)d_in[9];
    const float* W2  = (const float*)d_in[10];
    const float* as2 = (const float*)d_in[11];
    const float* ad2 = (const float*)d_in[12];
    const float* b2  = (const float*)d_in[13];
    float* out = (float*)d_out;

    float* ws = (float*)d_ws;
    size_t off = 0;
    unsigned* hb   = (unsigned*)(ws + off); off += (size_t)NN * 64;  // bf16 h, layers 0/1
    float* fA      = ws + off; off += (size_t)NN * 128;
    float* fB      = ws + off; off += (size_t)NN * 128;
    unsigned* hb40 = (unsigned*)(ws + off); off += (size_t)NN * 32;  // bf16 h, layer 2
    float* als     = ws + off; off += (size_t)NN * 8;
    float* ald     = ws + off; off += (size_t)NN * 8;
    int* ibase       = (int*)(ws + off);
    int* bucket_cnt  = ibase; ibase += NBUCK;
    int* bucket_off  = ibase; ibase += NBUCK + 2;
    int* bucket_cur  = ibase; ibase += NBUCK;
    int* row_ptr     = ibase; ibase += NCNT + 1;
    unsigned* ebkt   = (unsigned*)ibase; ibase += ETOT;
    int* src_sorted  = ibase; ibase += ETOT;

    const int TB = 256;

    // ---- CSR build (bucketed counting sort; shared by all 3 layers) ----
    hipMemsetAsync(bucket_cnt, 0, NBUCK * sizeof(int), stream);
    kA1<<<NBLK_A, 256, 0, stream>>>(ei, bucket_cnt);
    kA2<<<1, 1024, 0, stream>>>(bucket_cnt, bucket_off, bucket_cur);
    kA3<<<NBLK_A, 256, 0, stream>>>(ei, bucket_cur, ebkt);
    kB<<<NBUCK, 256, 0, stream>>>(bucket_off, ebkt, row_ptr, src_sorted);

    const int GG128 = (NN + 63) / 64;                 // 782
    const int GG40  = NN / 16;                        // 3125 (exact)
    const int GAGG4 = ((NN / 4) * 64 + TB - 1) / TB;  // 4 nodes per wave -> 3125

    // ---- Layer 0 ----
    gemm_att128<<<GG128, 256, 0, stream>>>(x, W0, as0, ad0, hb, als, ald);
    dst_agg128<true><<<GAGG4, TB, 0, stream>>>(row_ptr, src_sorted, als, ald, hb, b0, fA);

    // ---- Layer 1 ----
    gemm_att128<<<GG128, 256, 0, stream>>>(fA, W1, as1, ad1, hb, als, ald);
    dst_agg128<true><<<GAGG4, TB, 0, stream>>>(row_ptr, src_sorted, als, ald, hb, b1, fB);

    // ---- Layer 2 ----
    gemm_att40<<<GG40, 256, 0, stream>>>(fB, W2, as2, ad2, hb40, als, ald);
    dst_agg40<<<GAGG4, TB, 0, stream>>>(row_ptr, src_sorted, als, ald, hb40, b2, out);
}

// Round 11
// 215.784 us; speedup vs baseline: 1.4733x; 1.1321x over previous
//
#include <hip/hip_runtime.h>

#define NN    50000
#define ERAW  800000
#define ETOT  850000
#define NBUCK 782            // ceil(NN/64) buckets of 64 dst nodes
#define EPB_A 4096           // edges per block in bucketing passes
#define NBLK_A ((ETOT + EPB_A - 1) / EPB_A)   // 208
#define NCNT  (NBUCK * 64)   // 50048 (padded per-dst count array)

typedef __attribute__((ext_vector_type(8))) short bf16x8;
typedef __attribute__((ext_vector_type(4))) float f32x4;

union U16x8 { uint4 u; bf16x8 s; };
__device__ __forceinline__ bf16x8 as_bf(uint4 v) { U16x8 t; t.u = v; return t.s; }

__device__ __forceinline__ void edge_sd(const int* __restrict__ ei, int e, int& s, int& d) {
    if (e < ERAW) { s = ei[e]; d = ei[ERAW + e]; }
    else { int n = e - ERAW; s = n; d = n; }
}

// bf16 pack/unpack (RNE), 2 elements per uint: low16 = a, high16 = b
__device__ __forceinline__ unsigned pack_bf16x2(float a, float b) {
    unsigned ua = __float_as_uint(a), ub = __float_as_uint(b);
    ua += 0x7fffu + ((ua >> 16) & 1u);
    ub += 0x7fffu + ((ub >> 16) & 1u);
    return (ua >> 16) | (ub & 0xffff0000u);
}
__device__ __forceinline__ float2 unpack_bf16x2(unsigned v) {
    float2 r;
    r.x = __uint_as_float(v << 16);
    r.y = __uint_as_float(v & 0xffff0000u);
    return r;
}

// ---------------- CSR build: two-level bucketed counting sort ----------------
__global__ __launch_bounds__(256) void kA1(const int* __restrict__ ei, int* __restrict__ bucket_cnt) {
    __shared__ int lb[NBUCK];
    int t = threadIdx.x;
    for (int i = t; i < NBUCK; i += 256) lb[i] = 0;
    __syncthreads();
    int base = blockIdx.x * EPB_A;
    #pragma unroll 4
    for (int k = 0; k < EPB_A / 256; ++k) {
        int e = base + k * 256 + t;
        if (e < ETOT) {
            int s, d; edge_sd(ei, e, s, d); (void)s;
            atomicAdd(&lb[d >> 6], 1);
        }
    }
    __syncthreads();
    for (int i = t; i < NBUCK; i += 256) if (lb[i]) atomicAdd(&bucket_cnt[i], lb[i]);
}

__global__ void kA2(const int* __restrict__ bucket_cnt, int* __restrict__ bucket_off,
                    int* __restrict__ bucket_cur) {
    __shared__ int tmp[1024];
    int t = threadIdx.x;
    int v = (t < NBUCK) ? bucket_cnt[t] : 0;
    tmp[t] = v;
    __syncthreads();
    for (int off = 1; off < 1024; off <<= 1) {
        int u = (t >= off) ? tmp[t - off] : 0;
        __syncthreads();
        tmp[t] += u;
        __syncthreads();
    }
    if (t < NBUCK) { int ex = tmp[t] - v; bucket_off[t] = ex; bucket_cur[t] = ex; }
    if (t == 0) bucket_off[NBUCK] = ETOT;
}

__global__ __launch_bounds__(256) void kA3(const int* __restrict__ ei, int* __restrict__ bucket_cur,
                                           unsigned* __restrict__ ebkt) {
    __shared__ int lb[NBUCK];
    int t = threadIdx.x;
    for (int i = t; i < NBUCK; i += 256) lb[i] = 0;
    __syncthreads();
    int base = blockIdx.x * EPB_A;
    #pragma unroll 4
    for (int k = 0; k < EPB_A / 256; ++k) {
        int e = base + k * 256 + t;
        if (e < ETOT) {
            int s, d; edge_sd(ei, e, s, d); (void)s;
            atomicAdd(&lb[d >> 6], 1);
        }
    }
    __syncthreads();
    for (int i = t; i < NBUCK; i += 256) {
        int c = lb[i];
        lb[i] = c ? atomicAdd(&bucket_cur[i], c) : 0;
    }
    __syncthreads();
    #pragma unroll 4
    for (int k = 0; k < EPB_A / 256; ++k) {
        int e = base + k * 256 + t;
        if (e < ETOT) {
            int s, d; edge_sd(ei, e, s, d);
            int pos = atomicAdd(&lb[d >> 6], 1);
            ebkt[pos] = ((unsigned)d << 16) | (unsigned)s;
        }
    }
}

__global__ __launch_bounds__(256) void kB(const int* __restrict__ bucket_off,
                                          const unsigned* __restrict__ ebkt,
                                          int* __restrict__ row_ptr,
                                          int* __restrict__ src_sorted) {
    __shared__ int lc[64];
    int b = blockIdx.x, t = threadIdx.x;
    if (t < 64) lc[t] = 0;
    __syncthreads();
    int s0 = bucket_off[b], s1 = bucket_off[b + 1];
    for (int i = s0 + t; i < s1; i += 256) atomicAdd(&lc[(ebkt[i] >> 16) & 63], 1);
    __syncthreads();
    if (t < 64) {
        int v = lc[t];
        int inc = v;
        #pragma unroll
        for (int off = 1; off < 64; off <<= 1) {
            int u = __shfl_up(inc, off);
            if (t >= off) inc += u;
        }
        int ex = s0 + inc - v;
        row_ptr[b * 64 + t] = ex;
        lc[t] = ex;
    }
    __syncthreads();
    for (int i = s0 + t; i < s1; i += 256) {
        unsigned k = ebkt[i];
        int pos = atomicAdd(&lc[(k >> 16) & 63], 1);
        src_sorted[pos] = (int)(k & 0xffffu);
    }
}

// ---------------- prep: x -> bf16-packed, W0/W1 -> B-fragment layout ----------------
__global__ void conv_x(const float* __restrict__ x, unsigned* __restrict__ xb) {
    int g = blockIdx.x * 256 + threadIdx.x;   // one float4 -> uint2
    if (g >= NN * 32) return;
    float4 v = ((const float4*)x)[g];
    uint2 o;
    o.x = pack_bf16x2(v.x, v.y);
    o.y = pack_bf16x2(v.z, v.w);
    ((uint2*)xb)[g] = o;
}

// Wbp[(ct*4+kc)*64 + l] = uint4 of 8 bf16: col = ct*16+(l&15), k = kc*32+(l>>4)*8 ..+7
__global__ void prep_W(const float* __restrict__ W0, const float* __restrict__ W1,
                       unsigned* __restrict__ Wbp0, unsigned* __restrict__ Wbp1) {
    int g = blockIdx.x * 256 + threadIdx.x;   // 4096 total
    int which = g >> 11;
    int r = g & 2047;
    int ct = r >> 8, kc = (r >> 6) & 3, l = r & 63;
    int lr = l & 15, lg = l >> 4;
    int col = ct * 16 + lr, k0 = kc * 32 + lg * 8;
    const float* W = which ? W1 : W0;
    unsigned* O = which ? Wbp1 : Wbp0;
    uint4 o;
    o.x = pack_bf16x2(W[(k0 + 0) * 128 + col], W[(k0 + 1) * 128 + col]);
    o.y = pack_bf16x2(W[(k0 + 2) * 128 + col], W[(k0 + 3) * 128 + col]);
    o.z = pack_bf16x2(W[(k0 + 4) * 128 + col], W[(k0 + 5) * 128 + col]);
    o.w = pack_bf16x2(W[(k0 + 6) * 128 + col], W[(k0 + 7) * 128 + col]);
    ((uint4*)O)[(ct * 4 + kc) * 64 + l] = o;
}

// ---------------- MFMA GEMM (layers 0/1): hb[node][128] bf16 = xb @ W ----------------
// 256 threads = 4 waves; 64 nodes/block; wave w -> nodes n0+16w..+15, all 8 col-tiles.
// A: lane row=l&15, k-group=l>>4 (8 consecutive bf16 = uint4). D: col=lane&15, row=(l>>4)*4+j.
__global__ __launch_bounds__(256) void gemm_mfma128(
    const uint4* __restrict__ xb, const uint4* __restrict__ Wbp,
    unsigned* __restrict__ hb)
{
    int t = threadIdx.x;
    int wv = t >> 6, l = t & 63;
    int lr = l & 15, lg = l >> 4;
    int n0 = blockIdx.x * 64 + wv * 16;
    int nodeA = n0 + lr; if (nodeA >= NN) nodeA = NN - 1;
    const uint4* xr = xb + (size_t)nodeA * 16;
    uint4 a0 = xr[0 * 4 + lg];
    uint4 a1 = xr[1 * 4 + lg];
    uint4 a2 = xr[2 * 4 + lg];
    uint4 a3 = xr[3 * 4 + lg];
    #pragma unroll
    for (int ct = 0; ct < 8; ++ct) {
        const uint4* bp = Wbp + (size_t)(ct * 4) * 64;
        uint4 b0 = bp[0 * 64 + l];
        uint4 b1 = bp[1 * 64 + l];
        uint4 b2 = bp[2 * 64 + l];
        uint4 b3 = bp[3 * 64 + l];
        f32x4 acc = {0.f, 0.f, 0.f, 0.f};
        acc = __builtin_amdgcn_mfma_f32_16x16x32_bf16(as_bf(a0), as_bf(b0), acc, 0, 0, 0);
        acc = __builtin_amdgcn_mfma_f32_16x16x32_bf16(as_bf(a1), as_bf(b1), acc, 0, 0, 0);
        acc = __builtin_amdgcn_mfma_f32_16x16x32_bf16(as_bf(a2), as_bf(b2), acc, 0, 0, 0);
        acc = __builtin_amdgcn_mfma_f32_16x16x32_bf16(as_bf(a3), as_bf(b3), acc, 0, 0, 0);
        #pragma unroll
        for (int j = 0; j < 4; ++j) {
            float hv = acc[j];
            float nbv = __shfl_xor(hv, 1);
            int node = n0 + lg * 4 + j;
            if ((lr & 1) == 0 && node < NN)
                hb[(size_t)node * 64 + ct * 8 + (lr >> 1)] = pack_bf16x2(hv, nbv);
        }
    }
}

// ---------------- als/ald from bf16 h (streaming, 16 lanes/node) ----------------
__global__ void als_k(const unsigned* __restrict__ hb, const float* __restrict__ asrc,
                      const float* __restrict__ adst, float* __restrict__ als,
                      float* __restrict__ ald) {
    int g = blockIdx.x * blockDim.x + threadIdx.x;
    int node = g >> 4;
    if (node >= NN) return;
    int l = g & 15;                  // features 8l..8l+7, head = l>>1
    uint4 p = ((const uint4*)hb)[(size_t)node * 16 + l];
    float4 sa0 = ((const float4*)asrc)[2 * l], sa1 = ((const float4*)asrc)[2 * l + 1];
    float4 da0 = ((const float4*)adst)[2 * l], da1 = ((const float4*)adst)[2 * l + 1];
    float2 t0 = unpack_bf16x2(p.x), t1 = unpack_bf16x2(p.y);
    float2 t2 = unpack_bf16x2(p.z), t3 = unpack_bf16x2(p.w);
    float s1 = t0.x * sa0.x + t0.y * sa0.y + t1.x * sa0.z + t1.y * sa0.w
             + t2.x * sa1.x + t2.y * sa1.y + t3.x * sa1.z + t3.y * sa1.w;
    float s2 = t0.x * da0.x + t0.y * da0.y + t1.x * da0.z + t1.y * da0.w
             + t2.x * da1.x + t2.y * da1.y + t3.x * da1.z + t3.y * da1.w;
    s1 += __shfl_xor(s1, 1);
    s2 += __shfl_xor(s2, 1);
    if ((l & 1) == 0) {
        als[node * 8 + (l >> 1)] = s1;
        ald[node * 8 + (l >> 1)] = s2;
    }
}

// ---------------- GEMM + attention (layer 2: bf16 input, 128 -> 1x40) ----------------
__global__ __launch_bounds__(256) void gemm_att40(
    const unsigned* __restrict__ xbp, const float* __restrict__ W,
    const float* __restrict__ asrc, const float* __restrict__ adst,
    unsigned* __restrict__ hb40, float* __restrict__ als, float* __restrict__ ald)
{
    __shared__ float ws[128 * 40];
    __shared__ unsigned xs[16 * 64];
    int t = threadIdx.x;
    int n0 = blockIdx.x * 16;
    #pragma unroll
    for (int i = 0; i < 5; ++i) ((float4*)ws)[i * 256 + t] = ((const float4*)W)[i * 256 + t];
    ((uint4*)xs)[t] = ((const uint4*)xbp)[(size_t)n0 * 16 + t];
    __syncthreads();
    int w = t >> 6, c = t & 63;
    int cc = c < 40 ? c : 39;
    float acc[4] = {0.f, 0.f, 0.f, 0.f};
    #pragma unroll 4
    for (int kc = 0; kc < 32; ++kc) {
        float w0 = ws[(kc * 4 + 0) * 40 + cc];
        float w1 = ws[(kc * 4 + 1) * 40 + cc];
        float w2 = ws[(kc * 4 + 2) * 40 + cc];
        float w3 = ws[(kc * 4 + 3) * 40 + cc];
        #pragma unroll
        for (int i = 0; i < 4; ++i) {
            float2 f0 = unpack_bf16x2(xs[(4 * w + i) * 64 + kc * 2]);
            float2 f1 = unpack_bf16x2(xs[(4 * w + i) * 64 + kc * 2 + 1]);
            acc[i] = fmaf(f0.x, w0, acc[i]);
            acc[i] = fmaf(f0.y, w1, acc[i]);
            acc[i] = fmaf(f1.x, w2, acc[i]);
            acc[i] = fmaf(f1.y, w3, acc[i]);
        }
    }
    float a_s = (c < 40) ? asrc[c] : 0.f;
    float a_d = (c < 40) ? adst[c] : 0.f;
    #pragma unroll
    for (int i = 0; i < 4; ++i) {
        int n = n0 + 4 * w + i;
        float nb = __shfl_xor(acc[i], 1);
        if ((c & 1) == 0 && c < 40) hb40[(size_t)n * 32 + (c >> 1)] = pack_bf16x2(acc[i], nb);
        float v1 = acc[i] * a_s, v2 = acc[i] * a_d;
        #pragma unroll
        for (int m = 1; m < 64; m <<= 1) { v1 += __shfl_xor(v1, m); v2 += __shfl_xor(v2, m); }
        if (c == 0) { als[n] = v1; ald[n] = v2; }
    }
}

// ---------------- fused single-pass softmax + aggregate + finalize ----------------
// FOUR nodes per wave: 16 lanes/node; lane l covers features 8l..8l+7 (one uint4).
// Output written bf16-packed (next layer's GEMM input).
template<bool RELU>
__global__ void dst_agg128(const int* __restrict__ row_ptr, const int* __restrict__ src_sorted,
                           const float* __restrict__ als, const float* __restrict__ ald,
                           const unsigned* __restrict__ hb, const float* __restrict__ bias,
                           unsigned* __restrict__ outb)
{
    int wp = (blockIdx.x * blockDim.x + threadIdx.x) >> 6;
    if (wp >= NN / 4) return;
    int lane = threadIdx.x & 63;
    int q = lane >> 4, l = lane & 15;
    int node = 4 * wp + q;
    int myh = l >> 1;
    float aldv = ald[node * 8 + myh];
    int i = row_ptr[node], end = row_ptr[node + 1];
    float4 accA = make_float4(0.f, 0.f, 0.f, 0.f);
    float4 accB = make_float4(0.f, 0.f, 0.f, 0.f);
    float den = 0.f;
    while (__any(i + 4 <= end)) {
        if (i + 4 <= end) {
            int s0 = src_sorted[i], s1 = src_sorted[i + 1], s2 = src_sorted[i + 2], s3 = src_sorted[i + 3];
            float e0 = als[s0 * 8 + myh] + aldv;
            float e1 = als[s1 * 8 + myh] + aldv;
            float e2 = als[s2 * 8 + myh] + aldv;
            float e3 = als[s3 * 8 + myh] + aldv;
            uint4 p0 = ((const uint4*)(hb + (size_t)s0 * 64))[l];
            uint4 p1 = ((const uint4*)(hb + (size_t)s1 * 64))[l];
            uint4 p2 = ((const uint4*)(hb + (size_t)s2 * 64))[l];
            uint4 p3 = ((const uint4*)(hb + (size_t)s3 * 64))[l];
            e0 = e0 > 0.f ? e0 : 0.2f * e0;
            e1 = e1 > 0.f ? e1 : 0.2f * e1;
            e2 = e2 > 0.f ? e2 : 0.2f * e2;
            e3 = e3 > 0.f ? e3 : 0.2f * e3;
            float a0 = __expf(e0), a1 = __expf(e1), a2 = __expf(e2), a3 = __expf(e3);
            den += (a0 + a1) + (a2 + a3);
            float2 t0, t1;
            t0 = unpack_bf16x2(p0.x); t1 = unpack_bf16x2(p0.y);
            accA.x = fmaf(t0.x, a0, accA.x); accA.y = fmaf(t0.y, a0, accA.y);
            accA.z = fmaf(t1.x, a0, accA.z); accA.w = fmaf(t1.y, a0, accA.w);
            t0 = unpack_bf16x2(p0.z); t1 = unpack_bf16x2(p0.w);
            accB.x = fmaf(t0.x, a0, accB.x); accB.y = fmaf(t0.y, a0, accB.y);
            accB.z = fmaf(t1.x, a0, accB.z); accB.w = fmaf(t1.y, a0, accB.w);
            t0 = unpack_bf16x2(p1.x); t1 = unpack_bf16x2(p1.y);
            accA.x = fmaf(t0.x, a1, accA.x); accA.y = fmaf(t0.y, a1, accA.y);
            accA.z = fmaf(t1.x, a1, accA.z); accA.w = fmaf(t1.y, a1, accA.w);
            t0 = unpack_bf16x2(p1.z); t1 = unpack_bf16x2(p1.w);
            accB.x = fmaf(t0.x, a1, accB.x); accB.y = fmaf(t0.y, a1, accB.y);
            accB.z = fmaf(t1.x, a1, accB.z); accB.w = fmaf(t1.y, a1, accB.w);
            t0 = unpack_bf16x2(p2.x); t1 = unpack_bf16x2(p2.y);
            accA.x = fmaf(t0.x, a2, accA.x); accA.y = fmaf(t0.y, a2, accA.y);
            accA.z = fmaf(t1.x, a2, accA.z); accA.w = fmaf(t1.y, a2, accA.w);
            t0 = unpack_bf16x2(p2.z); t1 = unpack_bf16x2(p2.w);
            accB.x = fmaf(t0.x, a2, accB.x); accB.y = fmaf(t0.y, a2, accB.y);
            accB.z = fmaf(t1.x, a2, accB.z); accB.w = fmaf(t1.y, a2, accB.w);
            t0 = unpack_bf16x2(p3.x); t1 = unpack_bf16x2(p3.y);
            accA.x = fmaf(t0.x, a3, accA.x); accA.y = fmaf(t0.y, a3, accA.y);
            accA.z = fmaf(t1.x, a3, accA.z); accA.w = fmaf(t1.y, a3, accA.w);
            t0 = unpack_bf16x2(p3.z); t1 = unpack_bf16x2(p3.w);
            accB.x = fmaf(t0.x, a3, accB.x); accB.y = fmaf(t0.y, a3, accB.y);
            accB.z = fmaf(t1.x, a3, accB.z); accB.w = fmaf(t1.y, a3, accB.w);
            i += 4;
        }
    }
    while (__any(i < end)) {
        if (i < end) {
            int s0 = src_sorted[i];
            float e0 = als[s0 * 8 + myh] + aldv;
            e0 = e0 > 0.f ? e0 : 0.2f * e0;
            float a0 = __expf(e0);
            den += a0;
            uint4 p0 = ((const uint4*)(hb + (size_t)s0 * 64))[l];
            float2 t0 = unpack_bf16x2(p0.x), t1 = unpack_bf16x2(p0.y);
            accA.x = fmaf(t0.x, a0, accA.x); accA.y = fmaf(t0.y, a0, accA.y);
            accA.z = fmaf(t1.x, a0, accA.z); accA.w = fmaf(t1.y, a0, accA.w);
            t0 = unpack_bf16x2(p0.z); t1 = unpack_bf16x2(p0.w);
            accB.x = fmaf(t0.x, a0, accB.x); accB.y = fmaf(t0.y, a0, accB.y);
            accB.z = fmaf(t1.x, a0, accB.z); accB.w = fmaf(t1.y, a0, accB.w);
            ++i;
        }
    }
    float inv = 1.f / (den + 1e-16f);
    float4 bvA = ((const float4*)bias)[2 * l];
    float4 bvB = ((const float4*)bias)[2 * l + 1];
    float4 oA, oB;
    oA.x = accA.x * inv + bvA.x; oA.y = accA.y * inv + bvA.y;
    oA.z = accA.z * inv + bvA.z; oA.w = accA.w * inv + bvA.w;
    oB.x = accB.x * inv + bvB.x; oB.y = accB.y * inv + bvB.y;
    oB.z = accB.z * inv + bvB.z; oB.w = accB.w * inv + bvB.w;
    if (RELU) {
        oA.x = fmaxf(oA.x, 0.f); oA.y = fmaxf(oA.y, 0.f);
        oA.z = fmaxf(oA.z, 0.f); oA.w = fmaxf(oA.w, 0.f);
        oB.x = fmaxf(oB.x, 0.f); oB.y = fmaxf(oB.y, 0.f);
        oB.z = fmaxf(oB.z, 0.f); oB.w = fmaxf(oB.w, 0.f);
    }
    uint4 ob;
    ob.x = pack_bf16x2(oA.x, oA.y);
    ob.y = pack_bf16x2(oA.z, oA.w);
    ob.z = pack_bf16x2(oB.x, oB.y);
    ob.w = pack_bf16x2(oB.z, oB.w);
    ((uint4*)(outb + (size_t)node * 64))[l] = ob;
}

// H=1, C=40: FOUR nodes per wave (16 lanes each; lanes l<10 own uint2 feature pairs).
__global__ void dst_agg40(const int* __restrict__ row_ptr, const int* __restrict__ src_sorted,
                          const float* __restrict__ als, const float* __restrict__ ald,
                          const unsigned* __restrict__ hb40, const float* __restrict__ bias,
                          float* __restrict__ out)
{
    int wp = (blockIdx.x * blockDim.x + threadIdx.x) >> 6;
    if (wp >= NN / 4) return;
    int lane = threadIdx.x & 63;
    int q = lane >> 4, l = lane & 15;
    int node = 4 * wp + q;
    float aldv = ald[node];
    int i = row_ptr[node], end = row_ptr[node + 1];
    float4 acc = make_float4(0.f, 0.f, 0.f, 0.f);
    float den = 0.f;
    while (__any(i + 4 <= end)) {
        if (i + 4 <= end) {
            int s0 = src_sorted[i], s1 = src_sorted[i + 1], s2 = src_sorted[i + 2], s3 = src_sorted[i + 3];
            float e0 = als[s0] + aldv;
            float e1 = als[s1] + aldv;
            float e2 = als[s2] + aldv;
            float e3 = als[s3] + aldv;
            uint2 p0 = ((const uint2*)(hb40 + (size_t)s0 * 32))[l];
            uint2 p1 = ((const uint2*)(hb40 + (size_t)s1 * 32))[l];
            uint2 p2 = ((const uint2*)(hb40 + (size_t)s2 * 32))[l];
            uint2 p3 = ((const uint2*)(hb40 + (size_t)s3 * 32))[l];
            e0 = e0 > 0.f ? e0 : 0.2f * e0;
            e1 = e1 > 0.f ? e1 : 0.2f * e1;
            e2 = e2 > 0.f ? e2 : 0.2f * e2;
            e3 = e3 > 0.f ? e3 : 0.2f * e3;
            float a0 = __expf(e0), a1 = __expf(e1), a2 = __expf(e2), a3 = __expf(e3);
            den += (a0 + a1) + (a2 + a3);
            float2 u0 = unpack_bf16x2(p0.x), v0 = unpack_bf16x2(p0.y);
            float2 u1 = unpack_bf16x2(p1.x), v1 = unpack_bf16x2(p1.y);
            float2 u2 = unpack_bf16x2(p2.x), v2 = unpack_bf16x2(p2.y);
            float2 u3 = unpack_bf16x2(p3.x), v3 = unpack_bf16x2(p3.y);
            acc.x = fmaf(u0.x, a0, acc.x); acc.y = fmaf(u0.y, a0, acc.y);
            acc.z = fmaf(v0.x, a0, acc.z); acc.w = fmaf(v0.y, a0, acc.w);
            acc.x = fmaf(u1.x, a1, acc.x); acc.y = fmaf(u1.y, a1, acc.y);
            acc.z = fmaf(v1.x, a1, acc.z); acc.w = fmaf(v1.y, a1, acc.w);
            acc.x = fmaf(u2.x, a2, acc.x); acc.y = fmaf(u2.y, a2, acc.y);
            acc.z = fmaf(v2.x, a2, acc.z); acc.w = fmaf(v2.y, a2, acc.w);
            acc.x = fmaf(u3.x, a3, acc.x); acc.y = fmaf(u3.y, a3, acc.y);
            acc.z = fmaf(v3.x, a3, acc.z); acc.w = fmaf(v3.y, a3, acc.w);
            i += 4;
        }
    }
    while (__any(i < end)) {
        if (i < end) {
            int s0 = src_sorted[i];
            float e0 = als[s0] + aldv;
            e0 = e0 > 0.f ? e0 : 0.2f * e0;
            float a0 = __expf(e0);
            den += a0;
            uint2 p0 = ((const uint2*)(hb40 + (size_t)s0 * 32))[l];
            float2 u0 = unpack_bf16x2(p0.x), v0 = unpack_bf16x2(p0.y);
            acc.x = fmaf(u0.x, a0, acc.x); acc.y = fmaf(u0.y, a0, acc.y);
            acc.z = fmaf(v0.x, a0, acc.z); acc.w = fmaf(v0.y, a0, acc.w);
            ++i;
        }
    }
    if (l < 10) {
        float inv = 1.f / (den + 1e-16f);
        float4 bv = ((const float4*)bias)[l];
        float4 o;
        o.x = acc.x * inv + bv.x;
        o.y = acc.y * inv + bv.y;
        o.z = acc.z * inv + bv.z;
        o.w = acc.w * inv + bv.w;
        ((float4*)(out + (size_t)node * 40))[l] = o;
    }
}

extern "C" void kernel_launch(void* const* d_in, const int* in_sizes, int n_in,
                              void* d_out, int out_size, void* d_ws, size_t ws_size,
                              hipStream_t stream) {
    const float* x   = (const float*)d_in[0];
    const int*   ei  = (const int*)d_in[1];
    const float* W0  = (const float*)d_in[2];
    const float* as0 = (const float*)d_in[3];
    const float* ad0 = (const float*)d_in[4];
    const float* b0  = (const float*)d_in[5];
    const float* W1  = (const float*)d_in[6];
    const float* as1 = (const float*)d_in[7];
    const float* ad1 = (const float*)d_in[8];
    const float* b1  = (const float*)d_in[9];
    const float* W2  = (const float*)d_in[10];
    const float* as2 = (const float*)d_in[11];
    const float* ad2 = (const float*)d_in[12];
    const float* b2  = (const float*)d_in[13];
    float* out = (float*)d_out;

    float* ws = (float*)d_ws;
    size_t off = 0;
    unsigned* hb   = (unsigned*)(ws + off); off += (size_t)NN * 64;  // bf16 h (layers 0/1)
    unsigned* xb   = (unsigned*)(ws + off); off += (size_t)NN * 64;  // bf16 x
    unsigned* fAb  = (unsigned*)(ws + off); off += (size_t)NN * 64;  // bf16 layer-0 output
    unsigned* fBb  = (unsigned*)(ws + off); off += (size_t)NN * 64;  // bf16 layer-1 output
    unsigned* hb40 = (unsigned*)(ws + off); off += (size_t)NN * 32;  // bf16 h (layer 2)
    float* als     = ws + off; off += (size_t)NN * 8;
    float* ald     = ws + off; off += (size_t)NN * 8;
    unsigned* Wbp0 = (unsigned*)(ws + off); off += 8192;
    unsigned* Wbp1 = (unsigned*)(ws + off); off += 8192;
    int* ibase       = (int*)(ws + off);
    int* bucket_cnt  = ibase; ibase += NBUCK;
    int* bucket_off  = ibase; ibase += NBUCK + 2;
    int* bucket_cur  = ibase; ibase += NBUCK;
    int* row_ptr     = ibase; ibase += NCNT + 1;
    unsigned* ebkt   = (unsigned*)ibase; ibase += ETOT;
    int* src_sorted  = ibase; ibase += ETOT;

    const int TB = 256;

    // ---- CSR build (bucketed counting sort; shared by all 3 layers) ----
    hipMemsetAsync(bucket_cnt, 0, NBUCK * sizeof(int), stream);
    kA1<<<NBLK_A, 256, 0, stream>>>(ei, bucket_cnt);
    kA2<<<1, 1024, 0, stream>>>(bucket_cnt, bucket_off, bucket_cur);
    kA3<<<NBLK_A, 256, 0, stream>>>(ei, bucket_cur, ebkt);
    kB<<<NBUCK, 256, 0, stream>>>(bucket_off, ebkt, row_ptr, src_sorted);

    // ---- prep: bf16 conversions / weight prepack ----
    conv_x<<<(NN * 32 + TB - 1) / TB, TB, 0, stream>>>(x, xb);
    prep_W<<<16, 256, 0, stream>>>(W0, W1, Wbp0, Wbp1);

    const int GGM   = (NN + 63) / 64;                 // 782
    const int GG40  = NN / 16;                        // 3125 (exact)
    const int GALS  = NN * 16 / TB;                   // 3125 (exact)
    const int GAGG4 = ((NN / 4) * 64 + TB - 1) / TB;  // 3125

    // ---- Layer 0 ----
    gemm_mfma128<<<GGM, 256, 0, stream>>>((const uint4*)xb, (const uint4*)Wbp0, hb);
    als_k<<<GALS, TB, 0, stream>>>(hb, as0, ad0, als, ald);
    dst_agg128<true><<<GAGG4, TB, 0, stream>>>(row_ptr, src_sorted, als, ald, hb, b0, fAb);

    // ---- Layer 1 ----
    gemm_mfma128<<<GGM, 256, 0, stream>>>((const uint4*)fAb, (const uint4*)Wbp1, hb);
    als_k<<<GALS, TB, 0, stream>>>(hb, as1, ad1, als, ald);
    dst_agg128<true><<<GAGG4, TB, 0, stream>>>(row_ptr, src_sorted, als, ald, hb, b1, fBb);

    // ---- Layer 2 ----
    gemm_att40<<<GG40, 256, 0, stream>>>(fBb, W2, as2, ad2, hb40, als, ald);
    dst_agg40<<<GAGG4, TB, 0, stream>>>(row_ptr, src_sorted, als, ald, hb40, b2, out);
}